// Round 8
// baseline (461.260 us; speedup 1.0000x reference)
//
#include <hip/hip_runtime.h>
#include <math.h>

// ---------------- problem constants ----------------
#define NPX   4096      // 64*64
#define NSC   36864     // 9*4096 scores
#define NKPRE 2000
#define NKPOST 256
#define GKS   98        // head-gemm K splits (K chunk 512)
#define CSPL  8         // conv c-splits

// ---------------- ws layout (float offsets) ----------------
// feats region [0, 12845056) hosts, earlier in the timeline:
//   hpart [0, 8388608)         conv c-split partials (dead after k_convreduce)
//   h     [8388608, 9437184)   (dead after k_heads)
//   xpad  [9437184, 10552320)  padded input (dead after k_conv)
// part region [12845056, 15479296) hosts, earlier:
//   fmt [12845056, 13893632)   (dead after k_align)
//   wt  [13893632, 14483456)   (dead after k_conv)
#define F_FEATS 0
#define F_HPART 0
#define F_H     8388608
#define F_XPAD  9437184
#define F_PART  12845056
#define F_FMT   12845056
#define F_WT    13893632
#define F_UKEY  15479296
#define F_BX    15516160
#define F_BY    15553024
#define F_BW    15589888
#define F_BH    15626752
#define F_HIST  15663616
#define F_CAND  15729152
#define F_MASK  15737344
#define F_RBX   15865344
#define F_RBY   15867344
#define F_RBW   15869344
#define F_RBH   15871344
#define F_SEL   15873344
#define F_RXS   15873600
#define F_RYS   15873856
#define F_RWS   15874112
#define F_RHS   15874368
#define F_META  15874624
// total = 15,874,640 floats = 63,498,560 bytes (same proven footprint)

typedef unsigned long long u64;
typedef unsigned int u32;

// readlane broadcast of a u64 (index is wave-uniform) — VALU, not ds_bpermute
__device__ __forceinline__ u64 RL64(u64 v, int l) {
    u32 lo = (u32)__builtin_amdgcn_readlane((int)(u32)v, l);
    u32 hi = (u32)__builtin_amdgcn_readlane((int)(u32)(v >> 32), l);
    return ((u64)hi << 32) | lo;
}

// ---------------- init: zero hist + meta ----------------
__global__ void k_init(int* __restrict__ hist, int* __restrict__ meta) {
    int i = blockIdx.x * 256 + threadIdx.x;
    if (i < 65536) hist[i] = 0;
    if (i < 16) meta[i] = 0;
}

// ---------------- weight transpose: rpn_w [o][c][t] -> wt [c*9+t][o] ----------------
__global__ void k_wt(const float* __restrict__ rpn_w, float* __restrict__ wt) {
    int e = blockIdx.x * 256 + threadIdx.x;   // e < 589824
    int o = e & 255, rest = e >> 8;
    wt[rest * 256 + o] = rpn_w[o * 2304 + rest];
}

// ---------------- zero-pad input: x[c][64][64] -> xpad[c][66][66] ----------------
__global__ void k_pad(const float* __restrict__ x, float* __restrict__ xpad) {
    int c = blockIdx.x;
    for (int e = threadIdx.x; e < 4356; e += 256) {
        int row = e / 66, colp = e % 66;
        float v = 0.f;
        if (row >= 1 && row <= 64 && colp >= 1 && colp <= 64)
            v = x[c * 4096 + (row - 1) * 64 + (colp - 1)];
        xpad[c * 4356 + e] = v;
    }
}

// ---------------- transpose x (C,H,W) -> fmt (H*W, C) ----------------
__global__ void __launch_bounds__(256) k_transpose(const float* __restrict__ x,
                                                   float* __restrict__ fmt) {
    __shared__ float t[64][65];
    int pt = blockIdx.x;          // 64 px tiles
    int ct = blockIdx.y;          // 4 c tiles
    int tid = threadIdx.x;
    int px0 = pt * 64, c0 = ct * 64;
    int ln = tid & 63, sub = tid >> 6;
    for (int p = 0; p < 16; ++p) {
        int cl = p * 4 + sub;
        t[ln][cl] = x[(c0 + cl) * 4096 + px0 + ln];
    }
    __syncthreads();
    for (int p = 0; p < 16; ++p) {
        int pl = p * 4 + sub;
        fmt[(px0 + pl) * 256 + c0 + ln] = t[pl][ln];
    }
}

// ---------------- conv3x3 v5: padded input, 4px x 8oc tile, 8 c-splits ----------------
__global__ void __launch_bounds__(256) k_conv(const float* __restrict__ xpad,
                                              const float* __restrict__ wt,
                                              float* __restrict__ hpart) {
    __shared__ float lw[16 * 9 * 32];          // 4608 f = 18,432 B
    int tid = threadIdx.x;
    int col = tid & 63, ocg = tid >> 6;
    int y0 = blockIdx.x * 4;
    int oc0 = blockIdx.y * 32;
    int cb0 = blockIdx.z * 32;
    int off0 = y0 * 66 + col;
    float acc[4][8];
    #pragma unroll
    for (int r = 0; r < 4; ++r)
        #pragma unroll
        for (int j = 0; j < 8; ++j) acc[r][j] = 0.f;
    #pragma unroll 1
    for (int chunk = 0; chunk < 2; ++chunk) {
        int cbase = cb0 + chunk * 16;
        if (chunk) __syncthreads();
        #pragma unroll
        for (int i = 0; i < 18; ++i) {
            int e = tid + 256 * i;
            int cc = e / 288, rem = e % 288;
            lw[e] = wt[((cbase + cc) * 9 + (rem >> 5)) * 256 + oc0 + (rem & 31)];
        }
        __syncthreads();
        #pragma unroll 1
        for (int cc = 0; cc < 16; ++cc) {
            const float* xb = xpad + (size_t)(cbase + cc) * 4356 + off0;
            float xr[6][3];
            #pragma unroll
            for (int rr = 0; rr < 6; ++rr)
                #pragma unroll
                for (int d = 0; d < 3; ++d) xr[rr][d] = xb[rr * 66 + d];
            const float* lwc = &lw[cc * 288];
            #pragma unroll
            for (int t = 0; t < 9; ++t) {
                float4 wa = *(const float4*)&lwc[t * 32 + ocg * 8];
                float4 wb = *(const float4*)&lwc[t * 32 + ocg * 8 + 4];
                int dy = t / 3, dx = t % 3;
                #pragma unroll
                for (int r = 0; r < 4; ++r) {
                    float xv = xr[r + dy][dx];
                    acc[r][0] += xv * wa.x; acc[r][1] += xv * wa.y;
                    acc[r][2] += xv * wa.z; acc[r][3] += xv * wa.w;
                    acc[r][4] += xv * wb.x; acc[r][5] += xv * wb.y;
                    acc[r][6] += xv * wb.z; acc[r][7] += xv * wb.w;
                }
            }
        }
    }
    int px0 = y0 * 64 + col;
    #pragma unroll
    for (int j = 0; j < 8; ++j) {
        int oc = oc0 + ocg * 8 + j;
        float* dst = hpart + ((size_t)blockIdx.z * 256 + oc) * 4096 + px0;
        #pragma unroll
        for (int r = 0; r < 4; ++r) dst[r * 64] = acc[r][j];
    }
}

// ---------------- c-split reduce + bias -> h ----------------
__global__ void k_convreduce(const float* __restrict__ hpart,
                             const float* __restrict__ rpn_b,
                             float* __restrict__ h) {
    int e = blockIdx.x * 256 + threadIdx.x;   // < 1048576
    float s = 0.f;
    #pragma unroll
    for (int k = 0; k < CSPL; ++k) s += hpart[(size_t)k * 1048576 + e];
    h[e] = s + rpn_b[e >> 12];
}

// ---------------- rpn heads + decode + histogram ----------------
__global__ void __launch_bounds__(256) k_heads(const float* __restrict__ h,
        const float* __restrict__ cls_w, const float* __restrict__ cls_b,
        const float* __restrict__ tfm_w, const float* __restrict__ tfm_b,
        const float* __restrict__ anchors,
        float* __restrict__ out_cls, float* __restrict__ out_tfm,
        u32* __restrict__ ukey, float* __restrict__ bxp, float* __restrict__ byp,
        float* __restrict__ bwp, float* __restrict__ bhp, int* __restrict__ hist) {
    __shared__ float w[256 * 56];
    __shared__ float ds[32 * 55];
    int tid = threadIdx.x;
    int px0 = blockIdx.x * 32;
    for (int e = tid; e < 54 * 256; e += 256) {
        int o = e >> 8, c = e & 255;
        float v = (o < 18) ? cls_w[o * 256 + c] : tfm_w[(o - 18) * 256 + c];
        w[c * 56 + o] = v;
    }
    __syncthreads();
    int ploc = tid & 31, og = tid >> 5;
    int px = px0 + ploc;
    float acc[7];
    #pragma unroll
    for (int j = 0; j < 7; ++j) acc[j] = 0.f;
    for (int c = 0; c < 256; ++c) {
        float hv = h[c * 4096 + px];
        #pragma unroll
        for (int j = 0; j < 7; ++j) acc[j] += hv * w[c * 56 + og * 7 + j];
    }
    #pragma unroll
    for (int j = 0; j < 7; ++j) {
        int o = og * 7 + j;
        if (o < 54) {
            float b = (o < 18) ? cls_b[o] : tfm_b[o - 18];
            float val = acc[j] + b;
            if (o < 18) out_cls[o * 4096 + px] = val;
            else        out_tfm[(o - 18) * 4096 + px] = val;
            ds[ploc * 55 + o] = val;
        }
    }
    __syncthreads();
    for (int t = tid; t < 288; t += 256) {
        int a = t >> 5, p = t & 31;
        int pxx = px0 + p;
        float pos = ds[p * 55 + 2 * a];
        float neg = ds[p * 55 + 2 * a + 1];
        float d = pos - neg;
        float sc = 1.f / (1.f + expf(-d));
        float t0 = ds[p * 55 + 18 + 4 * a + 0];
        float t1 = ds[p * 55 + 18 + 4 * a + 1];
        float t2 = ds[p * 55 + 18 + 4 * a + 2];
        float t3 = ds[p * 55 + 18 + 4 * a + 3];
        float ah = anchors[a * 2 + 0], aw = anchors[a * 2 + 1];
        float jx = (float)(pxx & 63), iy = (float)(pxx >> 6);
        float bx = jx + aw * (t1 - 0.5f) / 16.f;
        float by = iy + ah * (t0 - 0.5f) / 16.f;
        float bw = aw / 16.f * expf(t3);
        float bh = ah / 16.f * expf(t2);
        bx = fminf(fmaxf(bx, 0.f), 63.f);
        by = fminf(fmaxf(by, 0.f), 63.f);
        bw = fminf(fmaxf(bx + bw, 0.f), 63.f) - bx;
        bh = fminf(fmaxf(by + bh, 0.f), 63.f) - by;
        int idx = a * 4096 + pxx;
        u32 bits = __float_as_uint(sc);
        u32 u = (bits & 0x80000000u) ? ~bits : (bits ^ 0x80000000u);
        ukey[idx] = u;
        bxp[idx] = bx; byp[idx] = by; bwp[idx] = bw; bhp[idx] = bh;
        atomicAdd(&hist[u >> 16], 1);
    }
}

// ---------------- find cutoff bin for top-2000 ----------------
__global__ void __launch_bounds__(1024) k_scan(const int* __restrict__ hist,
                                               int* __restrict__ meta) {
    __shared__ int s[1024];
    int t = threadIdx.x;
    int base = 65536 - 64 * (t + 1);
    int sum = 0;
    for (int i = 0; i < 64; ++i) sum += hist[base + i];
    s[t] = sum;
    __syncthreads();
    int own = sum;
    for (int off = 1; off < 1024; off <<= 1) {
        int v = (t >= off) ? s[t - off] : 0;
        __syncthreads();
        s[t] += v;
        __syncthreads();
    }
    int cum = s[t], prev = cum - own;
    if (prev < NKPRE && cum >= NKPRE) {
        int c = prev;
        int b = 65535 - 64 * t;
        for (int i = 0; i < 64; ++i) {
            c += hist[b - i];
            if (c >= NKPRE) { meta[0] = b - i; break; }
        }
    }
}

// ---------------- compact candidates (bin >= cutoff) ----------------
__global__ void k_compact(const u32* __restrict__ ukey, const int* __restrict__ meta,
                          u64* __restrict__ cand, int* __restrict__ cnt) {
    int i = blockIdx.x * 256 + threadIdx.x;
    if (i >= NSC) return;
    u32 u = ukey[i];
    if ((int)(u >> 16) >= meta[0]) {
        int pos = atomicAdd(cnt, 1);
        if (pos < 4096) cand[pos] = (((u64)(~u)) << 32) | (u32)i;
    }
}

// ---------------- bitonic sort 4096 -> top 2000 boxes ----------------
__global__ void __launch_bounds__(1024) k_sort(const u64* __restrict__ cand,
        const int* __restrict__ meta,
        const float* __restrict__ bxp, const float* __restrict__ byp,
        const float* __restrict__ bwp, const float* __restrict__ bhp,
        float* __restrict__ rbx, float* __restrict__ rby,
        float* __restrict__ rbw, float* __restrict__ rbh) {
    __shared__ u64 s[4096];
    int t = threadIdx.x;
    int cnt = meta[1]; if (cnt > 4096) cnt = 4096;
    for (int i = t; i < 4096; i += 1024)
        s[i] = (i < cnt) ? cand[i] : 0xFFFFFFFFFFFFFFFFULL;
    for (int k = 2; k <= 4096; k <<= 1)
        for (int j = k >> 1; j > 0; j >>= 1) {
            __syncthreads();
            for (int i = t; i < 4096; i += 1024) {
                int ixj = i ^ j;
                if (ixj > i) {
                    u64 a = s[i], b = s[ixj];
                    bool up = ((i & k) == 0);
                    if ((a > b) == up) { s[i] = b; s[ixj] = a; }
                }
            }
        }
    __syncthreads();
    for (int r = t; r < NKPRE; r += 1024) {
        int idx = (int)(u32)(s[r] & 0xFFFFFFFFULL);
        rbx[r] = bxp[idx]; rby[r] = byp[idx]; rbw[r] = bwp[idx]; rbh[r] = bhp[idx];
    }
}

// ---------------- IoU suppression bitmask ----------------
__global__ void __launch_bounds__(256) k_mask(const float* __restrict__ rbx,
        const float* __restrict__ rby, const float* __restrict__ rbw,
        const float* __restrict__ rbh, u64* __restrict__ mask) {
    int i = blockIdx.x;
    int lane = threadIdx.x & 63;
    int wave = threadIdx.x >> 6;
    float bxi = rbx[i], byi = rby[i], bwi = rbw[i], bhi = rbh[i];
    float x2i = bxi + bwi, y2i = byi + bhi, ari = bwi * bhi;
    for (int w = wave; w < 32; w += 4) {
        int j = w * 64 + lane;
        bool p = false;
        if (j < NKPRE && j > i) {
            float bxj = rbx[j], byj = rby[j], bwj = rbw[j], bhj = rbh[j];
            float x2j = bxj + bwj, y2j = byj + bhj, arj = bwj * bhj;
            float ix = fmaxf(bxi, bxj), iy = fmaxf(byi, byj);
            float iw = fmaxf(fminf(x2i, x2j) - ix, 0.f);
            float ih = fmaxf(fminf(y2i, y2j) - iy, 0.f);
            float inter = iw * ih;
            float iou = inter / (ari + arj - inter);
            p = iou > 0.7f;
        }
        u64 b = __ballot(p);
        if (lane == 0) mask[i * 32 + w] = b;
    }
}

// ---------------- greedy NMS v2: L2-warm + 32-deep prefetch + readlane broadcasts ----
__global__ void __launch_bounds__(64) k_nms(const u64* __restrict__ mask,
        const float* __restrict__ rbx, const float* __restrict__ rby,
        const float* __restrict__ rbw, const float* __restrict__ rbh,
        int* __restrict__ sel, float* __restrict__ rxs, float* __restrict__ rys,
        float* __restrict__ rws, float* __restrict__ rhs,
        u64* __restrict__ scratch) {
    __shared__ int klist[256];
    int lane = threadIdx.x;
    int lw = lane & 31;
    // ---- phase 0: warm mask (512 KB) into this XCD's L2 ----
    {
        const ulonglong2* m2 = (const ulonglong2*)mask;   // 32000 elements
        u64 acc = 0;
        #pragma unroll 25
        for (int it = lane; it < 32000; it += 64) {
            ulonglong2 v = m2[it];
            acc |= v.x | v.y;
        }
        scratch[lane] = acc;            // keep the loads alive
    }
    // ---- phase 1: serial greedy scan ----
    u64 removed = 0ULL;                 // lane w (w<32) holds removed bits for boxes w*64..w*64+63
    int kcount = 0;
    u64 pf[32];
    #pragma unroll
    for (int s = 0; s < 32; ++s) pf[s] = mask[s * 32 + lw];
    bool done = false;
    for (int ib = 0; ib < NKPRE; ib += 32) {
        if (done) break;
        int cw = ib >> 6;               // consume word (constant within batch)
        int iw = (ib + 32) >> 6;        // issue word   (constant within batch)
        u64 remC = RL64(removed, cw);
        u64 remI = RL64(removed, iw);
        #pragma unroll
        for (int s = 0; s < 32; ++s) {
            int ii = ib + s;
            u64 row = pf[s];
            int nx = ii + 32;
            if (!done && nx < NKPRE && !((remI >> (nx & 63)) & 1ULL))
                pf[s] = mask[(size_t)nx * 32 + lw];
            if (!done && ii < NKPRE && !((remC >> (ii & 63)) & 1ULL)) {
                if (lane == 0) klist[kcount] = ii;
                kcount++;
                if (lane < 32) removed |= row;
                remC |= RL64(row, cw);
                remI |= RL64(row, iw);
                if (kcount == NKPOST) done = true;
            }
        }
    }
    // ---- phase 2: fill with suppressed indices, ascending ----
    if (kcount < NKPOST) {
        for (int w = 0; w < 32 && kcount < NKPOST; ++w) {
            u64 wv = RL64(removed, w);
            int base = w << 6;
            for (int b = 0; b < 64; ++b) {
                int ii = base + b;
                if (ii >= NKPRE || kcount >= NKPOST) break;
                if ((wv >> b) & 1ULL) {
                    if (lane == 0) klist[kcount] = ii;
                    kcount++;
                }
            }
        }
    }
    __syncthreads();
    for (int s = lane; s < NKPOST; s += 64) {
        int id = klist[s];
        sel[s] = id;
        rxs[s] = rbx[id]; rys[s] = rby[id]; rws[s] = rbw[id]; rhs[s] = rbh[id];
    }
}

// ---------------- ROI align v2: grid (roi, cchunk, cellhalf) = 2048 blocks ----------
__global__ void __launch_bounds__(256) k_align(const float* __restrict__ fmt,
        const float* __restrict__ rxs, const float* __restrict__ rys,
        const float* __restrict__ rws, const float* __restrict__ rhs,
        float* __restrict__ feats) {
    __shared__ float buf[64 * 99];     // 25,344 B
    __shared__ int xs0[28], ys0[28];
    __shared__ float wxs[28], wys[28];
    int roi = blockIdx.x;
    int c0 = blockIdx.y * 64;
    int ch0 = blockIdx.z * 98;
    int tid = threadIdx.x;
    float rx = rxs[roi], ry = rys[roi], rw = rws[roi], rh = rhs[roi];
    if (tid < 28) {
        float g = rx + ((float)tid + 0.5f) * rw / 28.f;
        g = fminf(fmaxf(g, 0.f), 63.f);
        int x0 = (int)floorf(g); x0 = min(max(x0, 0), 62);
        xs0[tid] = x0; wxs[tid] = g - (float)x0;
        float g2 = ry + ((float)tid + 0.5f) * rh / 28.f;
        g2 = fminf(fmaxf(g2, 0.f), 63.f);
        int y0 = (int)floorf(g2); y0 = min(max(y0, 0), 62);
        ys0[tid] = y0; wys[tid] = g2 - (float)y0;
    }
    __syncthreads();
    int cl = tid & 63, cg = tid >> 6;
    for (int l = cg; l < 98; l += 4) {
        int cell = ch0 + l;
        int py = cell / 14, pxc = cell % 14;
        float m = -INFINITY;
        #pragma unroll
        for (int dy = 0; dy < 2; ++dy) {
            int sy = py * 2 + dy;
            int y0 = ys0[sy]; float wy = wys[sy];
            #pragma unroll
            for (int dx = 0; dx < 2; ++dx) {
                int sx = pxc * 2 + dx;
                int x0 = xs0[sx]; float wx = wxs[sx];
                int base = (y0 * 64 + x0) * 256 + c0 + cl;
                float f00 = fmt[base];
                float f10 = fmt[base + 256];
                float f01 = fmt[base + 64 * 256];
                float f11 = fmt[base + 64 * 256 + 256];
                float v = f00 * (1.f - wy) * (1.f - wx) + f01 * wy * (1.f - wx)
                        + f10 * (1.f - wy) * wx + f11 * wy * wx;
                m = fmaxf(m, v);
            }
        }
        buf[cl * 99 + l] = m;
    }
    __syncthreads();
    for (int e = tid; e < 64 * 98; e += 256) {
        int c = e / 98, l = e % 98;
        feats[(size_t)roi * 50176 + (c0 + c) * 196 + ch0 + l] = buf[c * 99 + l];
    }
}

// ---------------- head GEMM v5: grid (98, 8), block 128, thread tile 8roi x 4o ------
// LDS-traffic-minimizing: f-reads are wave-broadcast (free), 1 w-b128 per 32 FMA.
__global__ void __launch_bounds__(128) k_gemm(const float* __restrict__ feats,
        const float* __restrict__ head_w, float* __restrict__ part) {
    __shared__ float lf[64 * 32];    //  8 KB [kk][roi]
    __shared__ float lw[64 * 128];   // 32 KB [kk][o]
    int ks = blockIdx.x, rt = blockIdx.y;
    int tid = threadIdx.x;
    int og = tid & 31, rg = tid >> 5;      // og 0..31 (4 o each), rg 0..3 (8 roi each)
    int roi0 = rt * 32;
    int k0 = ks * 512;
    float acc[8][4];
    #pragma unroll
    for (int r = 0; r < 8; ++r)
        #pragma unroll
        for (int j = 0; j < 4; ++j) acc[r][j] = 0.f;
    for (int st = 0; st < 8; ++st) {
        int kb = k0 + st * 64;
        __syncthreads();
        {   // stage feats tile: 32 roi x 64 k (4 threads/roi, 4 float4 each)
            int r = tid >> 2, qb = tid & 3;
            const float* src = feats + (size_t)(roi0 + r) * 50176 + kb + qb * 16;
            #pragma unroll
            for (int q = 0; q < 4; ++q) {
                float4 v = *(const float4*)(src + q * 4);
                int kk = qb * 16 + q * 4;
                lf[(kk + 0) * 32 + r] = v.x;
                lf[(kk + 1) * 32 + r] = v.y;
                lf[(kk + 2) * 32 + r] = v.z;
                lf[(kk + 3) * 32 + r] = v.w;
            }
        }
        {   // stage weight tile: 128 o (105 valid) x 64 k (1 thread/o)
            int o = tid;
            if (o < 105) {
                const float* src = head_w + (size_t)o * 50176 + kb;
                #pragma unroll
                for (int q = 0; q < 16; ++q) {
                    float4 v = *(const float4*)(src + q * 4);
                    int kk = q * 4;
                    lw[(kk + 0) * 128 + o] = v.x;
                    lw[(kk + 1) * 128 + o] = v.y;
                    lw[(kk + 2) * 128 + o] = v.z;
                    lw[(kk + 3) * 128 + o] = v.w;
                }
            } else {
                #pragma unroll
                for (int q = 0; q < 64; ++q) lw[q * 128 + o] = 0.f;
            }
        }
        __syncthreads();
        #pragma unroll 8
        for (int kk = 0; kk < 64; ++kk) {
            float4 fa = *(const float4*)&lf[kk * 32 + rg * 8];
            float4 fb = *(const float4*)&lf[kk * 32 + rg * 8 + 4];
            float4 w = *(const float4*)&lw[kk * 128 + og * 4];
            float fv[8] = {fa.x, fa.y, fa.z, fa.w, fb.x, fb.y, fb.z, fb.w};
            float wv[4] = {w.x, w.y, w.z, w.w};
            #pragma unroll
            for (int r = 0; r < 8; ++r)
                #pragma unroll
                for (int j = 0; j < 4; ++j) acc[r][j] += fv[r] * wv[j];
        }
    }
    #pragma unroll
    for (int r = 0; r < 8; ++r) {
        int roi = roi0 + rg * 8 + r;
        #pragma unroll
        for (int j = 0; j < 4; ++j) {
            int o = og * 4 + j;
            if (o < 105) part[(size_t)ks * 26880 + roi * 105 + o] = acc[r][j];
        }
    }
}

// ---------------- deterministic K-split reduce + bias ----------------
__global__ void k_reduce(const float* __restrict__ part, const float* __restrict__ head_b,
                         float* __restrict__ out_cls, float* __restrict__ out_tfm) {
    int e = blockIdx.x * 256 + threadIdx.x;
    if (e >= 26880) return;
    int roi = e / 105, o = e % 105;
    float s = 0.f;
    for (int ks = 0; ks < GKS; ++ks) s += part[(size_t)ks * 26880 + e];
    s += head_b[o];
    if (o < 21) out_cls[roi * 21 + o] = s;
    else        out_tfm[roi * 84 + (o - 21)] = s;
}

// ---------------- argmax + final/proposal bbox ----------------
__global__ void __launch_bounds__(256) k_final(const float* __restrict__ out_cls,
        const float* __restrict__ out_tfm,
        const float* __restrict__ rxs, const float* __restrict__ rys,
        const float* __restrict__ rws, const float* __restrict__ rhs,
        float* __restrict__ prop, float* __restrict__ fbox) {
    int r = threadIdx.x;
    float best = out_cls[r * 21]; int det = 0;
    for (int o = 1; o < 21; ++o) {
        float v = out_cls[r * 21 + o];
        if (v > best) { best = v; det = o; }
    }
    float t0 = out_tfm[r * 84 + det * 4 + 0];
    float t1 = out_tfm[r * 84 + det * 4 + 1];
    float t2 = out_tfm[r * 84 + det * 4 + 2];
    float t3 = out_tfm[r * 84 + det * 4 + 3];
    float X = rxs[r] * 16.f, Y = rys[r] * 16.f, Wd = rws[r] * 16.f, Hd = rhs[r] * 16.f;
    float fx = X + Wd * t1, fy = Y + Hd * t0;
    float fw = Wd * expf(t3), fh = Hd * expf(t2);
    prop[r * 5 + 0] = 0.f; prop[r * 5 + 1] = X;  prop[r * 5 + 2] = Y;
    prop[r * 5 + 3] = Wd;  prop[r * 5 + 4] = Hd;
    fbox[r * 5 + 0] = 0.f; fbox[r * 5 + 1] = fx; fbox[r * 5 + 2] = fy;
    fbox[r * 5 + 3] = fw;  fbox[r * 5 + 4] = fh;
}

extern "C" void kernel_launch(void* const* d_in, const int* in_sizes, int n_in,
                              void* d_out, int out_size, void* d_ws, size_t ws_size,
                              hipStream_t stream) {
    const float* x      = (const float*)d_in[0];
    const float* rpn_w  = (const float*)d_in[1];
    const float* rpn_b  = (const float*)d_in[2];
    const float* cls_w  = (const float*)d_in[3];
    const float* cls_b  = (const float*)d_in[4];
    const float* tfm_w  = (const float*)d_in[5];
    const float* tfm_b  = (const float*)d_in[6];
    const float* head_w = (const float*)d_in[7];
    const float* head_b = (const float*)d_in[8];
    const float* anch   = (const float*)d_in[9];
    float* out = (float*)d_out;
    float* ws  = (float*)d_ws;

    float* hpart = ws + F_HPART;
    float* h     = ws + F_H;
    float* xpad  = ws + F_XPAD;
    float* fmt   = ws + F_FMT;
    float* wt    = ws + F_WT;
    float* feats = ws + F_FEATS;
    float* part  = ws + F_PART;
    u32*   ukey  = (u32*)(ws + F_UKEY);
    float* bxp   = ws + F_BX;
    float* byp   = ws + F_BY;
    float* bwp   = ws + F_BW;
    float* bhp   = ws + F_BH;
    int*   hist  = (int*)(ws + F_HIST);
    u64*   cand  = (u64*)(ws + F_CAND);
    u64*   mask  = (u64*)(ws + F_MASK);
    float* rbx   = ws + F_RBX;
    float* rby   = ws + F_RBY;
    float* rbw   = ws + F_RBW;
    float* rbh   = ws + F_RBH;
    int*   sel   = (int*)(ws + F_SEL);
    float* rxs   = ws + F_RXS;
    float* rys   = ws + F_RYS;
    float* rws_p = ws + F_RWS;
    float* rhs_p = ws + F_RHS;
    int*   meta  = (int*)(ws + F_META);

    float* out_rpncls = out + 0;
    float* out_rpntfm = out + 73728;
    float* out_prop   = out + 221184;
    float* out_fbox   = out + 222464;
    float* out_fcls   = out + 223744;
    float* out_ftfm   = out + 229120;

    k_init<<<256, 256, 0, stream>>>(hist, meta);
    k_wt<<<2304, 256, 0, stream>>>(rpn_w, wt);
    k_pad<<<256, 256, 0, stream>>>(x, xpad);
    k_transpose<<<dim3(64, 4), 256, 0, stream>>>(x, fmt);
    k_conv<<<dim3(16, 8, 8), 256, 0, stream>>>(xpad, wt, hpart);
    k_convreduce<<<4096, 256, 0, stream>>>(hpart, rpn_b, h);
    k_heads<<<128, 256, 0, stream>>>(h, cls_w, cls_b, tfm_w, tfm_b, anch,
                                     out_rpncls, out_rpntfm, ukey, bxp, byp, bwp, bhp, hist);
    k_scan<<<1, 1024, 0, stream>>>(hist, meta);
    k_compact<<<144, 256, 0, stream>>>(ukey, meta, cand, meta + 1);
    k_sort<<<1, 1024, 0, stream>>>(cand, meta, bxp, byp, bwp, bhp, rbx, rby, rbw, rbh);
    k_mask<<<2000, 256, 0, stream>>>(rbx, rby, rbw, rbh, mask);
    k_nms<<<1, 64, 0, stream>>>(mask, rbx, rby, rbw, rbh, sel, rxs, rys, rws_p, rhs_p,
                                cand);   // cand region is dead after k_sort -> warm scratch
    k_align<<<dim3(256, 4, 2), 256, 0, stream>>>(fmt, rxs, rys, rws_p, rhs_p, feats);
    k_gemm<<<dim3(98, 8), 128, 0, stream>>>(feats, head_w, part);
    k_reduce<<<105, 256, 0, stream>>>(part, head_b, out_fcls, out_ftfm);
    k_final<<<1, 256, 0, stream>>>(out_fcls, out_ftfm, rxs, rys, rws_p, rhs_p,
                                   out_prop, out_fbox);
}

// Round 9
// 437.698 us; speedup vs baseline: 1.0538x; 1.0538x over previous
//
#include <hip/hip_runtime.h>
#include <math.h>

// ---------------- problem constants ----------------
#define NPX   4096
#define NSC   36864
#define NKPRE 2000
#define NKPOST 256
#define GKS   98        // head-gemm K splits (K chunk 512)
#define CSPL  8         // conv c-splits

// ---------------- ws layout (float offsets) ----------------
// timeline aliases:
//  [0, 8388608):        hpart (k_conv->k_convreduce), then feats_b (bf16, k_align->k_gemm, 6422528 slots)
//  [8388608, 9437184):  h (k_convreduce->k_heads)   }  these four are all dead before k_gemm,
//  [9437184, 10552320): xpad (k_pad->k_conv)        }  so part (k_gemm->k_reduce, 2634240 f)
//  [10552320,11600896): fmt (k_transpose->k_align)  }  aliases [8388608, 11022848)
//  [11600896,12190720): wt (k_wt->k_conv)           }
//  [12190720,15000576): hwb (bf16 head_w, k_hwb->k_gemm, 5619712 ushorts)
//  [15000576, ...):     small persistent regions
#define F_FEATSB 0
#define F_HPART  0
#define F_H      8388608
#define F_PART   8388608
#define F_XPAD   9437184
#define F_FMT    10552320
#define F_WT     11600896
#define F_HWB    12190720
#define F_UKEY   15000576
#define F_BX     15037440
#define F_BY     15074304
#define F_BW     15111168
#define F_BH     15148032
#define F_HIST   15184896
#define F_CAND   15250432
#define F_MASK   15258624
#define F_RBX    15386624
#define F_RBY    15388624
#define F_RBW    15390624
#define F_RBH    15392624
#define F_SEL    15394624
#define F_RXS    15394880
#define F_RYS    15395136
#define F_RWS    15395392
#define F_RHS    15395648
#define F_META   15395904
// total = 15,395,920 floats = 61.6 MB (< proven 64.04 MB)

typedef unsigned long long u64;
typedef unsigned int u32;
typedef unsigned short ushort;
typedef __attribute__((ext_vector_type(8))) short short8;   // 8 bf16 (4 VGPRs)
typedef __attribute__((ext_vector_type(4))) float floatx4;  // MFMA acc

// RNE float -> bf16
__device__ __forceinline__ ushort f2bf(float f) {
    u32 b = __float_as_uint(f);
    b += 0x7FFFu + ((b >> 16) & 1u);
    return (ushort)(b >> 16);
}

// readlane broadcast of a u64 (wave-uniform index)
__device__ __forceinline__ u64 RL64(u64 v, int l) {
    u32 lo = (u32)__builtin_amdgcn_readlane((int)(u32)v, l);
    u32 hi = (u32)__builtin_amdgcn_readlane((int)(u32)(v >> 32), l);
    return ((u64)hi << 32) | lo;
}

// ---------------- init: zero hist + meta ----------------
__global__ void k_init(int* __restrict__ hist, int* __restrict__ meta) {
    int i = blockIdx.x * 256 + threadIdx.x;
    if (i < 65536) hist[i] = 0;
    if (i < 16) meta[i] = 0;
}

// ---------------- weight transpose: rpn_w [o][c][t] -> wt [c*9+t][o] ----------------
__global__ void k_wt(const float* __restrict__ rpn_w, float* __restrict__ wt) {
    int e = blockIdx.x * 256 + threadIdx.x;
    int o = e & 255, rest = e >> 8;
    wt[rest * 256 + o] = rpn_w[o * 2304 + rest];
}

// ---------------- head_w fp32 [105][50176] -> hwb bf16 [112][50176] (pad zeros) -----
__global__ void k_hwb(const float* __restrict__ head_w, ushort* __restrict__ hwb) {
    int e = (blockIdx.x * 256 + threadIdx.x) * 4;   // < 112*50176
    int o = e / 50176, k = e % 50176;
    ushort4 r;
    if (o < 105) {
        float4 v = *(const float4*)(head_w + (size_t)o * 50176 + k);
        r.x = f2bf(v.x); r.y = f2bf(v.y); r.z = f2bf(v.z); r.w = f2bf(v.w);
    } else {
        r.x = r.y = r.z = r.w = 0;
    }
    *(ushort4*)(hwb + (size_t)o * 50176 + k) = r;
}

// ---------------- zero-pad input: x[c][64][64] -> xpad[c][66][66] ----------------
__global__ void k_pad(const float* __restrict__ x, float* __restrict__ xpad) {
    int c = blockIdx.x;
    for (int e = threadIdx.x; e < 4356; e += 256) {
        int row = e / 66, colp = e % 66;
        float v = 0.f;
        if (row >= 1 && row <= 64 && colp >= 1 && colp <= 64)
            v = x[c * 4096 + (row - 1) * 64 + (colp - 1)];
        xpad[c * 4356 + e] = v;
    }
}

// ---------------- transpose x (C,H,W) -> fmt (H*W, C) ----------------
__global__ void __launch_bounds__(256) k_transpose(const float* __restrict__ x,
                                                   float* __restrict__ fmt) {
    __shared__ float t[64][65];
    int pt = blockIdx.x;
    int ct = blockIdx.y;
    int tid = threadIdx.x;
    int px0 = pt * 64, c0 = ct * 64;
    int ln = tid & 63, sub = tid >> 6;
    for (int p = 0; p < 16; ++p) {
        int cl = p * 4 + sub;
        t[ln][cl] = x[(c0 + cl) * 4096 + px0 + ln];
    }
    __syncthreads();
    for (int p = 0; p < 16; ++p) {
        int pl = p * 4 + sub;
        fmt[(px0 + pl) * 256 + c0 + ln] = t[pl][ln];
    }
}

// ---------------- conv3x3 v5: padded input, 4px x 8oc tile, 8 c-splits ----------------
__global__ void __launch_bounds__(256) k_conv(const float* __restrict__ xpad,
                                              const float* __restrict__ wt,
                                              float* __restrict__ hpart) {
    __shared__ float lw[16 * 9 * 32];
    int tid = threadIdx.x;
    int col = tid & 63, ocg = tid >> 6;
    int y0 = blockIdx.x * 4;
    int oc0 = blockIdx.y * 32;
    int cb0 = blockIdx.z * 32;
    int off0 = y0 * 66 + col;
    float acc[4][8];
    #pragma unroll
    for (int r = 0; r < 4; ++r)
        #pragma unroll
        for (int j = 0; j < 8; ++j) acc[r][j] = 0.f;
    #pragma unroll 1
    for (int chunk = 0; chunk < 2; ++chunk) {
        int cbase = cb0 + chunk * 16;
        if (chunk) __syncthreads();
        #pragma unroll
        for (int i = 0; i < 18; ++i) {
            int e = tid + 256 * i;
            int cc = e / 288, rem = e % 288;
            lw[e] = wt[((cbase + cc) * 9 + (rem >> 5)) * 256 + oc0 + (rem & 31)];
        }
        __syncthreads();
        #pragma unroll 1
        for (int cc = 0; cc < 16; ++cc) {
            const float* xb = xpad + (size_t)(cbase + cc) * 4356 + off0;
            float xr[6][3];
            #pragma unroll
            for (int rr = 0; rr < 6; ++rr)
                #pragma unroll
                for (int d = 0; d < 3; ++d) xr[rr][d] = xb[rr * 66 + d];
            const float* lwc = &lw[cc * 288];
            #pragma unroll
            for (int t = 0; t < 9; ++t) {
                float4 wa = *(const float4*)&lwc[t * 32 + ocg * 8];
                float4 wb = *(const float4*)&lwc[t * 32 + ocg * 8 + 4];
                int dy = t / 3, dx = t % 3;
                #pragma unroll
                for (int r = 0; r < 4; ++r) {
                    float xv = xr[r + dy][dx];
                    acc[r][0] += xv * wa.x; acc[r][1] += xv * wa.y;
                    acc[r][2] += xv * wa.z; acc[r][3] += xv * wa.w;
                    acc[r][4] += xv * wb.x; acc[r][5] += xv * wb.y;
                    acc[r][6] += xv * wb.z; acc[r][7] += xv * wb.w;
                }
            }
        }
    }
    int px0 = y0 * 64 + col;
    #pragma unroll
    for (int j = 0; j < 8; ++j) {
        int oc = oc0 + ocg * 8 + j;
        float* dst = hpart + ((size_t)blockIdx.z * 256 + oc) * 4096 + px0;
        #pragma unroll
        for (int r = 0; r < 4; ++r) dst[r * 64] = acc[r][j];
    }
}

// ---------------- c-split reduce + bias -> h ----------------
__global__ void k_convreduce(const float* __restrict__ hpart,
                             const float* __restrict__ rpn_b,
                             float* __restrict__ h) {
    int e = blockIdx.x * 256 + threadIdx.x;
    float s = 0.f;
    #pragma unroll
    for (int k = 0; k < CSPL; ++k) s += hpart[(size_t)k * 1048576 + e];
    h[e] = s + rpn_b[e >> 12];
}

// ---------------- rpn heads + decode + histogram ----------------
__global__ void __launch_bounds__(256) k_heads(const float* __restrict__ h,
        const float* __restrict__ cls_w, const float* __restrict__ cls_b,
        const float* __restrict__ tfm_w, const float* __restrict__ tfm_b,
        const float* __restrict__ anchors,
        float* __restrict__ out_cls, float* __restrict__ out_tfm,
        u32* __restrict__ ukey, float* __restrict__ bxp, float* __restrict__ byp,
        float* __restrict__ bwp, float* __restrict__ bhp, int* __restrict__ hist) {
    __shared__ float w[256 * 56];
    __shared__ float ds[32 * 55];
    int tid = threadIdx.x;
    int px0 = blockIdx.x * 32;
    for (int e = tid; e < 54 * 256; e += 256) {
        int o = e >> 8, c = e & 255;
        float v = (o < 18) ? cls_w[o * 256 + c] : tfm_w[(o - 18) * 256 + c];
        w[c * 56 + o] = v;
    }
    __syncthreads();
    int ploc = tid & 31, og = tid >> 5;
    int px = px0 + ploc;
    float acc[7];
    #pragma unroll
    for (int j = 0; j < 7; ++j) acc[j] = 0.f;
    for (int c = 0; c < 256; ++c) {
        float hv = h[c * 4096 + px];
        #pragma unroll
        for (int j = 0; j < 7; ++j) acc[j] += hv * w[c * 56 + og * 7 + j];
    }
    #pragma unroll
    for (int j = 0; j < 7; ++j) {
        int o = og * 7 + j;
        if (o < 54) {
            float b = (o < 18) ? cls_b[o] : tfm_b[o - 18];
            float val = acc[j] + b;
            if (o < 18) out_cls[o * 4096 + px] = val;
            else        out_tfm[(o - 18) * 4096 + px] = val;
            ds[ploc * 55 + o] = val;
        }
    }
    __syncthreads();
    for (int t = tid; t < 288; t += 256) {
        int a = t >> 5, p = t & 31;
        int pxx = px0 + p;
        float pos = ds[p * 55 + 2 * a];
        float neg = ds[p * 55 + 2 * a + 1];
        float d = pos - neg;
        float sc = 1.f / (1.f + expf(-d));
        float t0 = ds[p * 55 + 18 + 4 * a + 0];
        float t1 = ds[p * 55 + 18 + 4 * a + 1];
        float t2 = ds[p * 55 + 18 + 4 * a + 2];
        float t3 = ds[p * 55 + 18 + 4 * a + 3];
        float ah = anchors[a * 2 + 0], aw = anchors[a * 2 + 1];
        float jx = (float)(pxx & 63), iy = (float)(pxx >> 6);
        float bx = jx + aw * (t1 - 0.5f) / 16.f;
        float by = iy + ah * (t0 - 0.5f) / 16.f;
        float bw = aw / 16.f * expf(t3);
        float bh = ah / 16.f * expf(t2);
        bx = fminf(fmaxf(bx, 0.f), 63.f);
        by = fminf(fmaxf(by, 0.f), 63.f);
        bw = fminf(fmaxf(bx + bw, 0.f), 63.f) - bx;
        bh = fminf(fmaxf(by + bh, 0.f), 63.f) - by;
        int idx = a * 4096 + pxx;
        u32 bits = __float_as_uint(sc);
        u32 u = (bits & 0x80000000u) ? ~bits : (bits ^ 0x80000000u);
        ukey[idx] = u;
        bxp[idx] = bx; byp[idx] = by; bwp[idx] = bw; bhp[idx] = bh;
        atomicAdd(&hist[u >> 16], 1);
    }
}

// ---------------- find cutoff bin for top-2000 ----------------
__global__ void __launch_bounds__(1024) k_scan(const int* __restrict__ hist,
                                               int* __restrict__ meta) {
    __shared__ int s[1024];
    int t = threadIdx.x;
    int base = 65536 - 64 * (t + 1);
    int sum = 0;
    for (int i = 0; i < 64; ++i) sum += hist[base + i];
    s[t] = sum;
    __syncthreads();
    int own = sum;
    for (int off = 1; off < 1024; off <<= 1) {
        int v = (t >= off) ? s[t - off] : 0;
        __syncthreads();
        s[t] += v;
        __syncthreads();
    }
    int cum = s[t], prev = cum - own;
    if (prev < NKPRE && cum >= NKPRE) {
        int c = prev;
        int b = 65535 - 64 * t;
        for (int i = 0; i < 64; ++i) {
            c += hist[b - i];
            if (c >= NKPRE) { meta[0] = b - i; break; }
        }
    }
}

// ---------------- compact candidates (bin >= cutoff) ----------------
__global__ void k_compact(const u32* __restrict__ ukey, const int* __restrict__ meta,
                          u64* __restrict__ cand, int* __restrict__ cnt) {
    int i = blockIdx.x * 256 + threadIdx.x;
    if (i >= NSC) return;
    u32 u = ukey[i];
    if ((int)(u >> 16) >= meta[0]) {
        int pos = atomicAdd(cnt, 1);
        if (pos < 4096) cand[pos] = (((u64)(~u)) << 32) | (u32)i;
    }
}

// ---------------- bitonic sort 4096 -> top 2000 boxes ----------------
__global__ void __launch_bounds__(1024) k_sort(const u64* __restrict__ cand,
        const int* __restrict__ meta,
        const float* __restrict__ bxp, const float* __restrict__ byp,
        const float* __restrict__ bwp, const float* __restrict__ bhp,
        float* __restrict__ rbx, float* __restrict__ rby,
        float* __restrict__ rbw, float* __restrict__ rbh) {
    __shared__ u64 s[4096];
    int t = threadIdx.x;
    int cnt = meta[1]; if (cnt > 4096) cnt = 4096;
    for (int i = t; i < 4096; i += 1024)
        s[i] = (i < cnt) ? cand[i] : 0xFFFFFFFFFFFFFFFFULL;
    for (int k = 2; k <= 4096; k <<= 1)
        for (int j = k >> 1; j > 0; j >>= 1) {
            __syncthreads();
            for (int i = t; i < 4096; i += 1024) {
                int ixj = i ^ j;
                if (ixj > i) {
                    u64 a = s[i], b = s[ixj];
                    bool up = ((i & k) == 0);
                    if ((a > b) == up) { s[i] = b; s[ixj] = a; }
                }
            }
        }
    __syncthreads();
    for (int r = t; r < NKPRE; r += 1024) {
        int idx = (int)(u32)(s[r] & 0xFFFFFFFFULL);
        rbx[r] = bxp[idx]; rby[r] = byp[idx]; rbw[r] = bwp[idx]; rbh[r] = bhp[idx];
    }
}

// ---------------- IoU suppression bitmask ----------------
__global__ void __launch_bounds__(256) k_mask(const float* __restrict__ rbx,
        const float* __restrict__ rby, const float* __restrict__ rbw,
        const float* __restrict__ rbh, u64* __restrict__ mask) {
    int i = blockIdx.x;
    int lane = threadIdx.x & 63;
    int wave = threadIdx.x >> 6;
    float bxi = rbx[i], byi = rby[i], bwi = rbw[i], bhi = rbh[i];
    float x2i = bxi + bwi, y2i = byi + bhi, ari = bwi * bhi;
    for (int w = wave; w < 32; w += 4) {
        int j = w * 64 + lane;
        bool p = false;
        if (j < NKPRE && j > i) {
            float bxj = rbx[j], byj = rby[j], bwj = rbw[j], bhj = rbh[j];
            float x2j = bxj + bwj, y2j = byj + bhj, arj = bwj * bhj;
            float ix = fmaxf(bxi, bxj), iy = fmaxf(byi, byj);
            float iw = fmaxf(fminf(x2i, x2j) - ix, 0.f);
            float ih = fmaxf(fminf(y2i, y2j) - iy, 0.f);
            float inter = iw * ih;
            float iou = inter / (ari + arj - inter);
            p = iou > 0.7f;
        }
        u64 b = __ballot(p);
        if (lane == 0) mask[i * 32 + w] = b;
    }
}

// ---------------- greedy NMS v2 ----------------
__global__ void __launch_bounds__(64) k_nms(const u64* __restrict__ mask,
        const float* __restrict__ rbx, const float* __restrict__ rby,
        const float* __restrict__ rbw, const float* __restrict__ rbh,
        int* __restrict__ sel, float* __restrict__ rxs, float* __restrict__ rys,
        float* __restrict__ rws, float* __restrict__ rhs,
        u64* __restrict__ scratch) {
    __shared__ int klist[256];
    int lane = threadIdx.x;
    int lw = lane & 31;
    {   // warm mask into this XCD's L2
        const ulonglong2* m2 = (const ulonglong2*)mask;
        u64 acc = 0;
        #pragma unroll 25
        for (int it = lane; it < 32000; it += 64) {
            ulonglong2 v = m2[it];
            acc |= v.x | v.y;
        }
        scratch[lane] = acc;
    }
    u64 removed = 0ULL;
    int kcount = 0;
    u64 pf[32];
    #pragma unroll
    for (int s = 0; s < 32; ++s) pf[s] = mask[s * 32 + lw];
    bool done = false;
    for (int ib = 0; ib < NKPRE; ib += 32) {
        if (done) break;
        int cw = ib >> 6;
        int iw = (ib + 32) >> 6;
        u64 remC = RL64(removed, cw);
        u64 remI = RL64(removed, iw);
        #pragma unroll
        for (int s = 0; s < 32; ++s) {
            int ii = ib + s;
            u64 row = pf[s];
            int nx = ii + 32;
            if (!done && nx < NKPRE && !((remI >> (nx & 63)) & 1ULL))
                pf[s] = mask[(size_t)nx * 32 + lw];
            if (!done && ii < NKPRE && !((remC >> (ii & 63)) & 1ULL)) {
                if (lane == 0) klist[kcount] = ii;
                kcount++;
                if (lane < 32) removed |= row;
                remC |= RL64(row, cw);
                remI |= RL64(row, iw);
                if (kcount == NKPOST) done = true;
            }
        }
    }
    if (kcount < NKPOST) {
        for (int w = 0; w < 32 && kcount < NKPOST; ++w) {
            u64 wv = RL64(removed, w);
            int base = w << 6;
            for (int b = 0; b < 64; ++b) {
                int ii = base + b;
                if (ii >= NKPRE || kcount >= NKPOST) break;
                if ((wv >> b) & 1ULL) {
                    if (lane == 0) klist[kcount] = ii;
                    kcount++;
                }
            }
        }
    }
    __syncthreads();
    for (int s = lane; s < NKPOST; s += 64) {
        int id = klist[s];
        sel[s] = id;
        rxs[s] = rbx[id]; rys[s] = rby[id]; rws[s] = rbw[id]; rhs[s] = rbh[id];
    }
}

// ---------------- ROI align v3: bf16 output feats ----------------
__global__ void __launch_bounds__(256) k_align(const float* __restrict__ fmt,
        const float* __restrict__ rxs, const float* __restrict__ rys,
        const float* __restrict__ rws, const float* __restrict__ rhs,
        ushort* __restrict__ feats) {
    __shared__ float buf[64 * 99];
    __shared__ int xs0[28], ys0[28];
    __shared__ float wxs[28], wys[28];
    int roi = blockIdx.x;
    int c0 = blockIdx.y * 64;
    int ch0 = blockIdx.z * 98;
    int tid = threadIdx.x;
    float rx = rxs[roi], ry = rys[roi], rw = rws[roi], rh = rhs[roi];
    if (tid < 28) {
        float g = rx + ((float)tid + 0.5f) * rw / 28.f;
        g = fminf(fmaxf(g, 0.f), 63.f);
        int x0 = (int)floorf(g); x0 = min(max(x0, 0), 62);
        xs0[tid] = x0; wxs[tid] = g - (float)x0;
        float g2 = ry + ((float)tid + 0.5f) * rh / 28.f;
        g2 = fminf(fmaxf(g2, 0.f), 63.f);
        int y0 = (int)floorf(g2); y0 = min(max(y0, 0), 62);
        ys0[tid] = y0; wys[tid] = g2 - (float)y0;
    }
    __syncthreads();
    int cl = tid & 63, cg = tid >> 6;
    for (int l = cg; l < 98; l += 4) {
        int cell = ch0 + l;
        int py = cell / 14, pxc = cell % 14;
        float m = -INFINITY;
        #pragma unroll
        for (int dy = 0; dy < 2; ++dy) {
            int sy = py * 2 + dy;
            int y0 = ys0[sy]; float wy = wys[sy];
            #pragma unroll
            for (int dx = 0; dx < 2; ++dx) {
                int sx = pxc * 2 + dx;
                int x0 = xs0[sx]; float wx = wxs[sx];
                int base = (y0 * 64 + x0) * 256 + c0 + cl;
                float f00 = fmt[base];
                float f10 = fmt[base + 256];
                float f01 = fmt[base + 64 * 256];
                float f11 = fmt[base + 64 * 256 + 256];
                float v = f00 * (1.f - wy) * (1.f - wx) + f01 * wy * (1.f - wx)
                        + f10 * (1.f - wy) * wx + f11 * wy * wx;
                m = fmaxf(m, v);
            }
        }
        buf[cl * 99 + l] = m;
    }
    __syncthreads();
    for (int e = tid; e < 64 * 98; e += 256) {
        int c = e / 98, l = e % 98;
        feats[(size_t)roi * 50176 + (c0 + c) * 196 + ch0 + l] = f2bf(buf[c * 99 + l]);
    }
}

// ---------------- head GEMM v6: bf16 MFMA, no LDS, no barriers ----------------
// grid (98, 4), block 256 (4 waves). wave w: rois rt*64 + w*16 .. +15, all 112 o.
// per k-step: 1 A-frag + 7 B-frag 16B loads + 7x mfma_f32_16x16x32_bf16.
__global__ void __launch_bounds__(256) k_gemm(const ushort* __restrict__ fb,
        const ushort* __restrict__ hwb, float* __restrict__ part) {
    int ks = blockIdx.x, rt = blockIdx.y;
    int wave = threadIdx.x >> 6, lane = threadIdx.x & 63;
    int m16 = lane & 15, quad = lane >> 4;
    int roiBase = rt * 64 + wave * 16;
    int kb = ks * 512;
    const ushort* arow = fb + (size_t)(roiBase + m16) * 50176 + kb + quad * 8;
    const ushort* brow = hwb + (size_t)m16 * 50176 + kb + quad * 8;   // n = m16, o-tile via +t*16 rows
    floatx4 acc[7];
    #pragma unroll
    for (int t = 0; t < 7; ++t) acc[t] = (floatx4){0.f, 0.f, 0.f, 0.f};
    #pragma unroll 4
    for (int step = 0; step < 16; ++step) {
        short8 a = *(const short8*)(arow + step * 32);
        #pragma unroll
        for (int t = 0; t < 7; ++t) {
            short8 b = *(const short8*)(brow + (size_t)t * 16 * 50176 + step * 32);
            acc[t] = __builtin_amdgcn_mfma_f32_16x16x32_bf16(a, b, acc[t], 0, 0, 0);
        }
    }
    // D layout: lane holds D[m = quad*4 + reg][n = lane&15]
    float* pbase = part + (size_t)ks * 26880;
    #pragma unroll
    for (int t = 0; t < 7; ++t) {
        int o = t * 16 + m16;
        if (o < 105) {
            #pragma unroll
            for (int reg = 0; reg < 4; ++reg) {
                int roi = roiBase + quad * 4 + reg;
                pbase[roi * 105 + o] = acc[t][reg];
            }
        }
    }
}

// ---------------- deterministic K-split reduce + bias ----------------
__global__ void k_reduce(const float* __restrict__ part, const float* __restrict__ head_b,
                         float* __restrict__ out_cls, float* __restrict__ out_tfm) {
    int e = blockIdx.x * 256 + threadIdx.x;
    if (e >= 26880) return;
    int roi = e / 105, o = e % 105;
    float s = 0.f;
    for (int ks = 0; ks < GKS; ++ks) s += part[(size_t)ks * 26880 + e];
    s += head_b[o];
    if (o < 21) out_cls[roi * 21 + o] = s;
    else        out_tfm[roi * 84 + (o - 21)] = s;
}

// ---------------- argmax + final/proposal bbox ----------------
__global__ void __launch_bounds__(256) k_final(const float* __restrict__ out_cls,
        const float* __restrict__ out_tfm,
        const float* __restrict__ rxs, const float* __restrict__ rys,
        const float* __restrict__ rws, const float* __restrict__ rhs,
        float* __restrict__ prop, float* __restrict__ fbox) {
    int r = threadIdx.x;
    float best = out_cls[r * 21]; int det = 0;
    for (int o = 1; o < 21; ++o) {
        float v = out_cls[r * 21 + o];
        if (v > best) { best = v; det = o; }
    }
    float t0 = out_tfm[r * 84 + det * 4 + 0];
    float t1 = out_tfm[r * 84 + det * 4 + 1];
    float t2 = out_tfm[r * 84 + det * 4 + 2];
    float t3 = out_tfm[r * 84 + det * 4 + 3];
    float X = rxs[r] * 16.f, Y = rys[r] * 16.f, Wd = rws[r] * 16.f, Hd = rhs[r] * 16.f;
    float fx = X + Wd * t1, fy = Y + Hd * t0;
    float fw = Wd * expf(t3), fh = Hd * expf(t2);
    prop[r * 5 + 0] = 0.f; prop[r * 5 + 1] = X;  prop[r * 5 + 2] = Y;
    prop[r * 5 + 3] = Wd;  prop[r * 5 + 4] = Hd;
    fbox[r * 5 + 0] = 0.f; fbox[r * 5 + 1] = fx; fbox[r * 5 + 2] = fy;
    fbox[r * 5 + 3] = fw;  fbox[r * 5 + 4] = fh;
}

extern "C" void kernel_launch(void* const* d_in, const int* in_sizes, int n_in,
                              void* d_out, int out_size, void* d_ws, size_t ws_size,
                              hipStream_t stream) {
    const float* x      = (const float*)d_in[0];
    const float* rpn_w  = (const float*)d_in[1];
    const float* rpn_b  = (const float*)d_in[2];
    const float* cls_w  = (const float*)d_in[3];
    const float* cls_b  = (const float*)d_in[4];
    const float* tfm_w  = (const float*)d_in[5];
    const float* tfm_b  = (const float*)d_in[6];
    const float* head_w = (const float*)d_in[7];
    const float* head_b = (const float*)d_in[8];
    const float* anch   = (const float*)d_in[9];
    float* out = (float*)d_out;
    float* ws  = (float*)d_ws;

    float*  hpart  = ws + F_HPART;
    float*  h      = ws + F_H;
    float*  xpad   = ws + F_XPAD;
    float*  fmt    = ws + F_FMT;
    float*  wt     = ws + F_WT;
    ushort* featsb = (ushort*)(ws + F_FEATSB);
    ushort* hwb    = (ushort*)(ws + F_HWB);
    float*  part   = ws + F_PART;
    u32*    ukey   = (u32*)(ws + F_UKEY);
    float*  bxp    = ws + F_BX;
    float*  byp    = ws + F_BY;
    float*  bwp    = ws + F_BW;
    float*  bhp    = ws + F_BH;
    int*    hist   = (int*)(ws + F_HIST);
    u64*    cand   = (u64*)(ws + F_CAND);
    u64*    mask   = (u64*)(ws + F_MASK);
    float*  rbx    = ws + F_RBX;
    float*  rby    = ws + F_RBY;
    float*  rbw    = ws + F_RBW;
    float*  rbh    = ws + F_RBH;
    int*    sel    = (int*)(ws + F_SEL);
    float*  rxs    = ws + F_RXS;
    float*  rys    = ws + F_RYS;
    float*  rws_p  = ws + F_RWS;
    float*  rhs_p  = ws + F_RHS;
    int*    meta   = (int*)(ws + F_META);

    float* out_rpncls = out + 0;
    float* out_rpntfm = out + 73728;
    float* out_prop   = out + 221184;
    float* out_fbox   = out + 222464;
    float* out_fcls   = out + 223744;
    float* out_ftfm   = out + 229120;

    k_init<<<256, 256, 0, stream>>>(hist, meta);
    k_wt<<<2304, 256, 0, stream>>>(rpn_w, wt);
    k_hwb<<<5488, 256, 0, stream>>>(head_w, hwb);
    k_pad<<<256, 256, 0, stream>>>(x, xpad);
    k_transpose<<<dim3(64, 4), 256, 0, stream>>>(x, fmt);
    k_conv<<<dim3(16, 8, 8), 256, 0, stream>>>(xpad, wt, hpart);
    k_convreduce<<<4096, 256, 0, stream>>>(hpart, rpn_b, h);
    k_heads<<<128, 256, 0, stream>>>(h, cls_w, cls_b, tfm_w, tfm_b, anch,
                                     out_rpncls, out_rpntfm, ukey, bxp, byp, bwp, bhp, hist);
    k_scan<<<1, 1024, 0, stream>>>(hist, meta);
    k_compact<<<144, 256, 0, stream>>>(ukey, meta, cand, meta + 1);
    k_sort<<<1, 1024, 0, stream>>>(cand, meta, bxp, byp, bwp, bhp, rbx, rby, rbw, rbh);
    k_mask<<<2000, 256, 0, stream>>>(rbx, rby, rbw, rbh, mask);
    k_nms<<<1, 64, 0, stream>>>(mask, rbx, rby, rbw, rbh, sel, rxs, rys, rws_p, rhs_p,
                                cand);
    k_align<<<dim3(256, 4, 2), 256, 0, stream>>>(fmt, rxs, rys, rws_p, rhs_p, featsb);
    k_gemm<<<dim3(98, 4), 256, 0, stream>>>(featsb, hwb, part);
    k_reduce<<<105, 256, 0, stream>>>(part, head_b, out_fcls, out_ftfm);
    k_final<<<1, 256, 0, stream>>>(out_fcls, out_ftfm, rxs, rys, rws_p, rhs_p,
                                   out_prop, out_fbox);
}

// Round 11
// 395.197 us; speedup vs baseline: 1.1672x; 1.1075x over previous
//
#include <hip/hip_runtime.h>
#include <math.h>

// ---------------- problem constants ----------------
#define NPX   4096
#define NSC   36864
#define NKPRE 2000
#define NKPOST 256
#define GKS   98        // head-gemm K splits (K chunk 512)
#define CSPL  4         // conv K-splits (18 of 72 ksteps each)

// ---------------- ws layout (float offsets) ----------------
// sizes (float slots): hpart 4,194,304 | part 2,634,240 (aliases hpart)
//   h 1,048,576 | fmt 1,048,576 | xbh/xbl 557,568 ea | wbh/wbl 294,912 ea
//   featsb 6,422,528 (12,845,056 ushorts; ALIASES xb/wb — dead after k_conv,
//   k_align runs later) | hwb 2,809,856 (5,619,712 ushorts)
#define F_HPART  0
#define F_PART   0
#define F_H      4194304
#define F_FMT    5242880
#define F_XBH    6291456
#define F_XBL    6849024
#define F_WBH    7406592
#define F_WBL    7701504
#define F_FEATSB 6291456
#define F_HWB    12713984
#define F_UKEY   15523840
#define F_BX     15560704
#define F_BY     15597568
#define F_BW     15634432
#define F_BH     15671296
#define F_HIST   15708160
#define F_CAND   15773696
#define F_MASK   15781888
#define F_RBX    15909888
#define F_RBY    15911888
#define F_RBW    15913888
#define F_RBH    15915888
#define F_SEL    15917888
#define F_RXS    15918144
#define F_RYS    15918400
#define F_RWS    15918656
#define F_RHS    15918912
#define F_META   15919168
// total = 15,919,184 floats = 63,676,736 bytes (< proven 64,037,184)

typedef unsigned long long u64;
typedef unsigned int u32;
typedef unsigned short ushort;
typedef __attribute__((ext_vector_type(8))) short short8;   // 8 bf16
typedef __attribute__((ext_vector_type(4))) float floatx4;  // MFMA acc

__device__ __forceinline__ ushort f2bf(float f) {
    u32 b = __float_as_uint(f);
    b += 0x7FFFu + ((b >> 16) & 1u);
    return (ushort)(b >> 16);
}
__device__ __forceinline__ float bf2f(ushort h) {
    return __uint_as_float(((u32)h) << 16);
}
__device__ __forceinline__ u64 RL64(u64 v, int l) {
    u32 lo = (u32)__builtin_amdgcn_readlane((int)(u32)v, l);
    u32 hi = (u32)__builtin_amdgcn_readlane((int)(u32)(v >> 32), l);
    return ((u64)hi << 32) | lo;
}

// ---------------- init: zero hist + meta ----------------
__global__ void k_init(int* __restrict__ hist, int* __restrict__ meta) {
    int i = blockIdx.x * 256 + threadIdx.x;
    if (i < 65536) hist[i] = 0;
    if (i < 16) meta[i] = 0;
}

// ---------------- head_w fp32 -> hwb bf16 [112][50176] ----------------
__global__ void k_hwb(const float* __restrict__ head_w, ushort* __restrict__ hwb) {
    int e = (blockIdx.x * 256 + threadIdx.x) * 4;
    int o = e / 50176, k = e % 50176;
    ushort4 r;
    if (o < 105) {
        float4 v = *(const float4*)(head_w + (size_t)o * 50176 + k);
        r.x = f2bf(v.x); r.y = f2bf(v.y); r.z = f2bf(v.z); r.w = f2bf(v.w);
    } else {
        r.x = r.y = r.z = r.w = 0;
    }
    *(ushort4*)(hwb + (size_t)o * 50176 + k) = r;
}

// ---------------- transpose x (C,H,W) -> fmt (H*W, C) ----------------
__global__ void __launch_bounds__(256) k_transpose(const float* __restrict__ x,
                                                   float* __restrict__ fmt) {
    __shared__ float t[64][65];
    int pt = blockIdx.x;
    int ct = blockIdx.y;
    int tid = threadIdx.x;
    int px0 = pt * 64, c0 = ct * 64;
    int ln = tid & 63, sub = tid >> 6;
    for (int p = 0; p < 16; ++p) {
        int cl = p * 4 + sub;
        t[ln][cl] = x[(c0 + cl) * 4096 + px0 + ln];
    }
    __syncthreads();
    for (int p = 0; p < 16; ++p) {
        int pl = p * 4 + sub;
        fmt[(px0 + pl) * 256 + c0 + ln] = t[pl][ln];
    }
}

// ---------------- build padded px-major split-bf16 image from fmt ----------------
__global__ void k_xb(const float* __restrict__ fmt, ushort* __restrict__ xbh,
                     ushort* __restrict__ xbl) {
    int e = blockIdx.x * 256 + threadIdx.x;     // < 278784
    int p = e >> 6, cq = (e & 63) * 4;
    int yy = p / 66, xx = p % 66;
    float4 v = {0.f, 0.f, 0.f, 0.f};
    if (yy >= 1 && yy <= 64 && xx >= 1 && xx <= 64)
        v = *(const float4*)&fmt[((yy - 1) * 64 + (xx - 1)) * 256 + cq];
    ushort4 h, l;
    h.x = f2bf(v.x); l.x = f2bf(v.x - bf2f(h.x));
    h.y = f2bf(v.y); l.y = f2bf(v.y - bf2f(h.y));
    h.z = f2bf(v.z); l.z = f2bf(v.z - bf2f(h.z));
    h.w = f2bf(v.w); l.w = f2bf(v.w - bf2f(h.w));
    *(ushort4*)&xbh[(size_t)p * 256 + cq] = h;
    *(ushort4*)&xbl[(size_t)p * 256 + cq] = l;
}

// ---------------- build per-tap split-bf16 weights wb{h,l}[t][oc][c] ----------------
__global__ void k_wb(const float* __restrict__ rpn_w, ushort* __restrict__ wbh,
                     ushort* __restrict__ wbl) {
    int e = blockIdx.x * 256 + threadIdx.x;     // e = t*65536 + oc*256 + c
    int c = e & 255, oc = (e >> 8) & 255, t = e >> 16;
    float v = rpn_w[oc * 2304 + c * 9 + t];
    ushort h = f2bf(v);
    wbh[e] = h;
    wbl[e] = f2bf(v - bf2f(h));
}

// ---------------- conv3x3 v6: split-bf16 MFMA implicit GEMM ----------------
__global__ void __launch_bounds__(256) k_conv(const ushort* __restrict__ xbh,
        const ushort* __restrict__ xbl, const ushort* __restrict__ wbh,
        const ushort* __restrict__ wbl, float* __restrict__ hpart) {
    __shared__ ushort lah[64 * 40], lal[64 * 40];
    __shared__ ushort lbh[64 * 40], lbl[64 * 40];
    int y0 = blockIdx.x;
    int oc0 = blockIdx.y * 64;
    int ksp = blockIdx.z;
    int tid = threadIdx.x;
    int wave = tid >> 6, lane = tid & 63;
    int m16 = lane & 15, quad = lane >> 4;
    floatx4 acc[4];
    #pragma unroll
    for (int nt = 0; nt < 4; ++nt) acc[nt] = (floatx4){0.f, 0.f, 0.f, 0.f};
    int sr = tid >> 2, sch = (tid & 3) * 8;
    for (int ki = ksp * 18; ki < ksp * 18 + 18; ++ki) {
        int t = ki >> 3, cb = ki & 7;
        int dy = t / 3, dx = t % 3;
        __syncthreads();
        {
            int rA0 = (y0 + dy) * 66 + dx;
            size_t g = (size_t)(rA0 + sr) * 256 + cb * 32 + sch;
            *(short8*)&lah[sr * 40 + sch] = *(const short8*)&xbh[g];
            *(short8*)&lal[sr * 40 + sch] = *(const short8*)&xbl[g];
        }
        {
            size_t g = (size_t)t * 65536 + (size_t)(oc0 + sr) * 256 + cb * 32 + sch;
            *(short8*)&lbh[sr * 40 + sch] = *(const short8*)&wbh[g];
            *(short8*)&lbl[sr * 40 + sch] = *(const short8*)&wbl[g];
        }
        __syncthreads();
        short8 ah = *(const short8*)&lah[(wave * 16 + m16) * 40 + quad * 8];
        short8 al = *(const short8*)&lal[(wave * 16 + m16) * 40 + quad * 8];
        #pragma unroll
        for (int nt = 0; nt < 4; ++nt) {
            short8 bh = *(const short8*)&lbh[(nt * 16 + m16) * 40 + quad * 8];
            short8 bl = *(const short8*)&lbl[(nt * 16 + m16) * 40 + quad * 8];
            acc[nt] = __builtin_amdgcn_mfma_f32_16x16x32_bf16(al, bh, acc[nt], 0, 0, 0);
            acc[nt] = __builtin_amdgcn_mfma_f32_16x16x32_bf16(ah, bl, acc[nt], 0, 0, 0);
            acc[nt] = __builtin_amdgcn_mfma_f32_16x16x32_bf16(ah, bh, acc[nt], 0, 0, 0);
        }
    }
    float* hp = hpart + (size_t)ksp * 1048576;
    #pragma unroll
    for (int nt = 0; nt < 4; ++nt) {
        int oc = oc0 + nt * 16 + m16;
        #pragma unroll
        for (int reg = 0; reg < 4; ++reg) {
            int px = y0 * 64 + wave * 16 + quad * 4 + reg;
            hp[oc * 4096 + px] = acc[nt][reg];
        }
    }
}

// ---------------- K-split reduce + bias -> h ----------------
__global__ void k_convreduce(const float* __restrict__ hpart,
                             const float* __restrict__ rpn_b,
                             float* __restrict__ h) {
    int e = blockIdx.x * 256 + threadIdx.x;
    float s = 0.f;
    #pragma unroll
    for (int k = 0; k < CSPL; ++k) s += hpart[(size_t)k * 1048576 + e];
    h[e] = s + rpn_b[e >> 12];
}

// ---------------- rpn heads + decode + histogram ----------------
__global__ void __launch_bounds__(256) k_heads(const float* __restrict__ h,
        const float* __restrict__ cls_w, const float* __restrict__ cls_b,
        const float* __restrict__ tfm_w, const float* __restrict__ tfm_b,
        const float* __restrict__ anchors,
        float* __restrict__ out_cls, float* __restrict__ out_tfm,
        u32* __restrict__ ukey, float* __restrict__ bxp, float* __restrict__ byp,
        float* __restrict__ bwp, float* __restrict__ bhp, int* __restrict__ hist) {
    __shared__ float w[256 * 56];
    __shared__ float ds[32 * 55];
    int tid = threadIdx.x;
    int px0 = blockIdx.x * 32;
    for (int e = tid; e < 54 * 256; e += 256) {
        int o = e >> 8, c = e & 255;
        float v = (o < 18) ? cls_w[o * 256 + c] : tfm_w[(o - 18) * 256 + c];
        w[c * 56 + o] = v;
    }
    __syncthreads();
    int ploc = tid & 31, og = tid >> 5;
    int px = px0 + ploc;
    float acc[7];
    #pragma unroll
    for (int j = 0; j < 7; ++j) acc[j] = 0.f;
    for (int c = 0; c < 256; ++c) {
        float hv = h[c * 4096 + px];
        #pragma unroll
        for (int j = 0; j < 7; ++j) acc[j] += hv * w[c * 56 + og * 7 + j];
    }
    #pragma unroll
    for (int j = 0; j < 7; ++j) {
        int o = og * 7 + j;
        if (o < 54) {
            float b = (o < 18) ? cls_b[o] : tfm_b[o - 18];
            float val = acc[j] + b;
            if (o < 18) out_cls[o * 4096 + px] = val;
            else        out_tfm[(o - 18) * 4096 + px] = val;
            ds[ploc * 55 + o] = val;
        }
    }
    __syncthreads();
    for (int t = tid; t < 288; t += 256) {
        int a = t >> 5, p = t & 31;
        int pxx = px0 + p;
        float pos = ds[p * 55 + 2 * a];
        float neg = ds[p * 55 + 2 * a + 1];
        float d = pos - neg;
        float sc = 1.f / (1.f + expf(-d));
        float t0 = ds[p * 55 + 18 + 4 * a + 0];
        float t1 = ds[p * 55 + 18 + 4 * a + 1];
        float t2 = ds[p * 55 + 18 + 4 * a + 2];
        float t3 = ds[p * 55 + 18 + 4 * a + 3];
        float ah = anchors[a * 2 + 0], aw = anchors[a * 2 + 1];
        float jx = (float)(pxx & 63), iy = (float)(pxx >> 6);
        float bx = jx + aw * (t1 - 0.5f) / 16.f;
        float by = iy + ah * (t0 - 0.5f) / 16.f;
        float bw = aw / 16.f * expf(t3);
        float bh = ah / 16.f * expf(t2);
        bx = fminf(fmaxf(bx, 0.f), 63.f);
        by = fminf(fmaxf(by, 0.f), 63.f);
        bw = fminf(fmaxf(bx + bw, 0.f), 63.f) - bx;
        bh = fminf(fmaxf(by + bh, 0.f), 63.f) - by;
        int idx = a * 4096 + pxx;
        u32 bits = __float_as_uint(sc);
        u32 u = (bits & 0x80000000u) ? ~bits : (bits ^ 0x80000000u);
        ukey[idx] = u;
        bxp[idx] = bx; byp[idx] = by; bwp[idx] = bw; bhp[idx] = bh;
        atomicAdd(&hist[u >> 16], 1);
    }
}

// ---------------- find cutoff bin for top-2000 ----------------
__global__ void __launch_bounds__(1024) k_scan(const int* __restrict__ hist,
                                               int* __restrict__ meta) {
    __shared__ int s[1024];
    int t = threadIdx.x;
    int base = 65536 - 64 * (t + 1);
    int sum = 0;
    for (int i = 0; i < 64; ++i) sum += hist[base + i];
    s[t] = sum;
    __syncthreads();
    int own = sum;
    for (int off = 1; off < 1024; off <<= 1) {
        int v = (t >= off) ? s[t - off] : 0;
        __syncthreads();
        s[t] += v;
        __syncthreads();
    }
    int cum = s[t], prev = cum - own;
    if (prev < NKPRE && cum >= NKPRE) {
        int c = prev;
        int b = 65535 - 64 * t;
        for (int i = 0; i < 64; ++i) {
            c += hist[b - i];
            if (c >= NKPRE) { meta[0] = b - i; break; }
        }
    }
}

// ---------------- compact candidates (bin >= cutoff) ----------------
__global__ void k_compact(const u32* __restrict__ ukey, const int* __restrict__ meta,
                          u64* __restrict__ cand, int* __restrict__ cnt) {
    int i = blockIdx.x * 256 + threadIdx.x;
    if (i >= NSC) return;
    u32 u = ukey[i];
    if ((int)(u >> 16) >= meta[0]) {
        int pos = atomicAdd(cnt, 1);
        if (pos < 4096) cand[pos] = (((u64)(~u)) << 32) | (u32)i;
    }
}

// ---------------- bitonic sort 4096 -> top 2000 boxes ----------------
__global__ void __launch_bounds__(1024) k_sort(const u64* __restrict__ cand,
        const int* __restrict__ meta,
        const float* __restrict__ bxp, const float* __restrict__ byp,
        const float* __restrict__ bwp, const float* __restrict__ bhp,
        float* __restrict__ rbx, float* __restrict__ rby,
        float* __restrict__ rbw, float* __restrict__ rbh) {
    __shared__ u64 s[4096];
    int t = threadIdx.x;
    int cnt = meta[1]; if (cnt > 4096) cnt = 4096;
    for (int i = t; i < 4096; i += 1024)
        s[i] = (i < cnt) ? cand[i] : 0xFFFFFFFFFFFFFFFFULL;
    for (int k = 2; k <= 4096; k <<= 1)
        for (int j = k >> 1; j > 0; j >>= 1) {
            __syncthreads();
            for (int i = t; i < 4096; i += 1024) {
                int ixj = i ^ j;
                if (ixj > i) {
                    u64 a = s[i], b = s[ixj];
                    bool up = ((i & k) == 0);
                    if ((a > b) == up) { s[i] = b; s[ixj] = a; }
                }
            }
        }
    __syncthreads();
    for (int r = t; r < NKPRE; r += 1024) {
        int idx = (int)(u32)(s[r] & 0xFFFFFFFFULL);
        rbx[r] = bxp[idx]; rby[r] = byp[idx]; rbw[r] = bwp[idx]; rbh[r] = bhp[idx];
    }
}

// ---------------- IoU suppression bitmask ----------------
__global__ void __launch_bounds__(256) k_mask(const float* __restrict__ rbx,
        const float* __restrict__ rby, const float* __restrict__ rbw,
        const float* __restrict__ rbh, u64* __restrict__ mask) {
    int i = blockIdx.x;
    int lane = threadIdx.x & 63;
    int wave = threadIdx.x >> 6;
    float bxi = rbx[i], byi = rby[i], bwi = rbw[i], bhi = rbh[i];
    float x2i = bxi + bwi, y2i = byi + bhi, ari = bwi * bhi;
    for (int w = wave; w < 32; w += 4) {
        int j = w * 64 + lane;
        bool p = false;
        if (j < NKPRE && j > i) {
            float bxj = rbx[j], byj = rby[j], bwj = rbw[j], bhj = rbh[j];
            float x2j = bxj + bwj, y2j = byj + bhj, arj = bwj * bhj;
            float ix = fmaxf(bxi, bxj), iy = fmaxf(byi, byj);
            float iw = fmaxf(fminf(x2i, x2j) - ix, 0.f);
            float ih = fmaxf(fminf(y2i, y2j) - iy, 0.f);
            float inter = iw * ih;
            float iou = inter / (ari + arj - inter);
            p = iou > 0.7f;
        }
        u64 b = __ballot(p);
        if (lane == 0) mask[i * 32 + w] = b;
    }
}

// ---------------- greedy NMS v2 ----------------
__global__ void __launch_bounds__(64) k_nms(const u64* __restrict__ mask,
        const float* __restrict__ rbx, const float* __restrict__ rby,
        const float* __restrict__ rbw, const float* __restrict__ rbh,
        int* __restrict__ sel, float* __restrict__ rxs, float* __restrict__ rys,
        float* __restrict__ rws, float* __restrict__ rhs,
        u64* __restrict__ scratch) {
    __shared__ int klist[256];
    int lane = threadIdx.x;
    int lw = lane & 31;
    {
        const ulonglong2* m2 = (const ulonglong2*)mask;
        u64 acc = 0;
        #pragma unroll 25
        for (int it = lane; it < 32000; it += 64) {
            ulonglong2 v = m2[it];
            acc |= v.x | v.y;
        }
        scratch[lane] = acc;
    }
    u64 removed = 0ULL;
    int kcount = 0;
    u64 pf[32];
    #pragma unroll
    for (int s = 0; s < 32; ++s) pf[s] = mask[s * 32 + lw];
    bool done = false;
    for (int ib = 0; ib < NKPRE; ib += 32) {
        if (done) break;
        int cw = ib >> 6;
        int iw = (ib + 32) >> 6;
        u64 remC = RL64(removed, cw);
        u64 remI = RL64(removed, iw);
        #pragma unroll
        for (int s = 0; s < 32; ++s) {
            int ii = ib + s;
            u64 row = pf[s];
            int nx = ii + 32;
            if (!done && nx < NKPRE && !((remI >> (nx & 63)) & 1ULL))
                pf[s] = mask[(size_t)nx * 32 + lw];
            if (!done && ii < NKPRE && !((remC >> (ii & 63)) & 1ULL)) {
                if (lane == 0) klist[kcount] = ii;
                kcount++;
                if (lane < 32) removed |= row;
                remC |= RL64(row, cw);
                remI |= RL64(row, iw);
                if (kcount == NKPOST) done = true;
            }
        }
    }
    if (kcount < NKPOST) {
        for (int w = 0; w < 32 && kcount < NKPOST; ++w) {
            u64 wv = RL64(removed, w);
            int base = w << 6;
            for (int b = 0; b < 64; ++b) {
                int ii = base + b;
                if (ii >= NKPRE || kcount >= NKPOST) break;
                if ((wv >> b) & 1ULL) {
                    if (lane == 0) klist[kcount] = ii;
                    kcount++;
                }
            }
        }
    }
    __syncthreads();
    for (int s = lane; s < NKPOST; s += 64) {
        int id = klist[s];
        sel[s] = id;
        rxs[s] = rbx[id]; rys[s] = rby[id]; rws[s] = rbw[id]; rhs[s] = rbh[id];
    }
}

// ---------------- ROI align v3: bf16 output feats ----------------
__global__ void __launch_bounds__(256) k_align(const float* __restrict__ fmt,
        const float* __restrict__ rxs, const float* __restrict__ rys,
        const float* __restrict__ rws, const float* __restrict__ rhs,
        ushort* __restrict__ feats) {
    __shared__ float buf[64 * 99];
    __shared__ int xs0[28], ys0[28];
    __shared__ float wxs[28], wys[28];
    int roi = blockIdx.x;
    int c0 = blockIdx.y * 64;
    int ch0 = blockIdx.z * 98;
    int tid = threadIdx.x;
    float rx = rxs[roi], ry = rys[roi], rw = rws[roi], rh = rhs[roi];
    if (tid < 28) {
        float g = rx + ((float)tid + 0.5f) * rw / 28.f;
        g = fminf(fmaxf(g, 0.f), 63.f);
        int x0 = (int)floorf(g); x0 = min(max(x0, 0), 62);
        xs0[tid] = x0; wxs[tid] = g - (float)x0;
        float g2 = ry + ((float)tid + 0.5f) * rh / 28.f;
        g2 = fminf(fmaxf(g2, 0.f), 63.f);
        int y0 = (int)floorf(g2); y0 = min(max(y0, 0), 62);
        ys0[tid] = y0; wys[tid] = g2 - (float)y0;
    }
    __syncthreads();
    int cl = tid & 63, cg = tid >> 6;
    for (int l = cg; l < 98; l += 4) {
        int cell = ch0 + l;
        int py = cell / 14, pxc = cell % 14;
        float m = -INFINITY;
        #pragma unroll
        for (int dy = 0; dy < 2; ++dy) {
            int sy = py * 2 + dy;
            int y0 = ys0[sy]; float wy = wys[sy];
            #pragma unroll
            for (int dx = 0; dx < 2; ++dx) {
                int sx = pxc * 2 + dx;
                int x0 = xs0[sx]; float wx = wxs[sx];
                int base = (y0 * 64 + x0) * 256 + c0 + cl;
                float f00 = fmt[base];
                float f10 = fmt[base + 256];
                float f01 = fmt[base + 64 * 256];
                float f11 = fmt[base + 64 * 256 + 256];
                float v = f00 * (1.f - wy) * (1.f - wx) + f01 * wy * (1.f - wx)
                        + f10 * (1.f - wy) * wx + f11 * wy * wx;
                m = fmaxf(m, v);
            }
        }
        buf[cl * 99 + l] = m;
    }
    __syncthreads();
    for (int e = tid; e < 64 * 98; e += 256) {
        int c = e / 98, l = e % 98;
        feats[(size_t)roi * 50176 + (c0 + c) * 196 + ch0 + l] = f2bf(buf[c * 99 + l]);
    }
}

// ---------------- head GEMM v6: bf16 MFMA, no LDS, no barriers ----------------
__global__ void __launch_bounds__(256) k_gemm(const ushort* __restrict__ fb,
        const ushort* __restrict__ hwb, float* __restrict__ part) {
    int ks = blockIdx.x, rt = blockIdx.y;
    int wave = threadIdx.x >> 6, lane = threadIdx.x & 63;
    int m16 = lane & 15, quad = lane >> 4;
    int roiBase = rt * 64 + wave * 16;
    int kb = ks * 512;
    const ushort* arow = fb + (size_t)(roiBase + m16) * 50176 + kb + quad * 8;
    const ushort* brow = hwb + (size_t)m16 * 50176 + kb + quad * 8;
    floatx4 acc[7];
    #pragma unroll
    for (int t = 0; t < 7; ++t) acc[t] = (floatx4){0.f, 0.f, 0.f, 0.f};
    #pragma unroll 4
    for (int step = 0; step < 16; ++step) {
        short8 a = *(const short8*)(arow + step * 32);
        #pragma unroll
        for (int t = 0; t < 7; ++t) {
            short8 b = *(const short8*)(brow + (size_t)t * 16 * 50176 + step * 32);
            acc[t] = __builtin_amdgcn_mfma_f32_16x16x32_bf16(a, b, acc[t], 0, 0, 0);
        }
    }
    float* pbase = part + (size_t)ks * 26880;
    #pragma unroll
    for (int t = 0; t < 7; ++t) {
        int o = t * 16 + m16;
        if (o < 105) {
            #pragma unroll
            for (int reg = 0; reg < 4; ++reg) {
                int roi = roiBase + quad * 4 + reg;
                pbase[roi * 105 + o] = acc[t][reg];
            }
        }
    }
}

// ---------------- deterministic K-split reduce + bias ----------------
__global__ void k_reduce(const float* __restrict__ part, const float* __restrict__ head_b,
                         float* __restrict__ out_cls, float* __restrict__ out_tfm) {
    int e = blockIdx.x * 256 + threadIdx.x;
    if (e >= 26880) return;
    int roi = e / 105, o = e % 105;
    float s = 0.f;
    for (int ks = 0; ks < GKS; ++ks) s += part[(size_t)ks * 26880 + e];
    s += head_b[o];
    if (o < 21) out_cls[roi * 21 + o] = s;
    else        out_tfm[roi * 84 + (o - 21)] = s;
}

// ---------------- argmax + final/proposal bbox ----------------
__global__ void __launch_bounds__(256) k_final(const float* __restrict__ out_cls,
        const float* __restrict__ out_tfm,
        const float* __restrict__ rxs, const float* __restrict__ rys,
        const float* __restrict__ rws, const float* __restrict__ rhs,
        float* __restrict__ prop, float* __restrict__ fbox) {
    int r = threadIdx.x;
    float best = out_cls[r * 21]; int det = 0;
    for (int o = 1; o < 21; ++o) {
        float v = out_cls[r * 21 + o];
        if (v > best) { best = v; det = o; }
    }
    float t0 = out_tfm[r * 84 + det * 4 + 0];
    float t1 = out_tfm[r * 84 + det * 4 + 1];
    float t2 = out_tfm[r * 84 + det * 4 + 2];
    float t3 = out_tfm[r * 84 + det * 4 + 3];
    float X = rxs[r] * 16.f, Y = rys[r] * 16.f, Wd = rws[r] * 16.f, Hd = rhs[r] * 16.f;
    float fx = X + Wd * t1, fy = Y + Hd * t0;
    float fw = Wd * expf(t3), fh = Hd * expf(t2);
    prop[r * 5 + 0] = 0.f; prop[r * 5 + 1] = X;  prop[r * 5 + 2] = Y;
    prop[r * 5 + 3] = Wd;  prop[r * 5 + 4] = Hd;
    fbox[r * 5 + 0] = 0.f; fbox[r * 5 + 1] = fx; fbox[r * 5 + 2] = fy;
    fbox[r * 5 + 3] = fw;  fbox[r * 5 + 4] = fh;
}

extern "C" void kernel_launch(void* const* d_in, const int* in_sizes, int n_in,
                              void* d_out, int out_size, void* d_ws, size_t ws_size,
                              hipStream_t stream) {
    const float* x      = (const float*)d_in[0];
    const float* rpn_w  = (const float*)d_in[1];
    const float* rpn_b  = (const float*)d_in[2];
    const float* cls_w  = (const float*)d_in[3];
    const float* cls_b  = (const float*)d_in[4];
    const float* tfm_w  = (const float*)d_in[5];
    const float* tfm_b  = (const float*)d_in[6];
    const float* head_w = (const float*)d_in[7];
    const float* head_b = (const float*)d_in[8];
    const float* anch   = (const float*)d_in[9];
    float* out = (float*)d_out;
    float* ws  = (float*)d_ws;

    float*  hpart  = ws + F_HPART;
    float*  h      = ws + F_H;
    float*  fmt    = ws + F_FMT;
    ushort* xbh    = (ushort*)(ws + F_XBH);
    ushort* xbl    = (ushort*)(ws + F_XBL);
    ushort* wbh    = (ushort*)(ws + F_WBH);
    ushort* wbl    = (ushort*)(ws + F_WBL);
    ushort* featsb = (ushort*)(ws + F_FEATSB);
    ushort* hwb    = (ushort*)(ws + F_HWB);
    float*  part   = ws + F_PART;
    u32*    ukey   = (u32*)(ws + F_UKEY);
    float*  bxp    = ws + F_BX;
    float*  byp    = ws + F_BY;
    float*  bwp    = ws + F_BW;
    float*  bhp    = ws + F_BH;
    int*    hist   = (int*)(ws + F_HIST);
    u64*    cand   = (u64*)(ws + F_CAND);
    u64*    mask   = (u64*)(ws + F_MASK);
    float*  rbx    = ws + F_RBX;
    float*  rby    = ws + F_RBY;
    float*  rbw    = ws + F_RBW;
    float*  rbh    = ws + F_RBH;
    int*    sel    = (int*)(ws + F_SEL);
    float*  rxs    = ws + F_RXS;
    float*  rys    = ws + F_RYS;
    float*  rws_p  = ws + F_RWS;
    float*  rhs_p  = ws + F_RHS;
    int*    meta   = (int*)(ws + F_META);

    float* out_rpncls = out + 0;
    float* out_rpntfm = out + 73728;
    float* out_prop   = out + 221184;
    float* out_fbox   = out + 222464;
    float* out_fcls   = out + 223744;
    float* out_ftfm   = out + 229120;

    k_init<<<256, 256, 0, stream>>>(hist, meta);
    k_hwb<<<5488, 256, 0, stream>>>(head_w, hwb);
    k_transpose<<<dim3(64, 4), 256, 0, stream>>>(x, fmt);
    k_xb<<<1089, 256, 0, stream>>>(fmt, xbh, xbl);
    k_wb<<<2304, 256, 0, stream>>>(rpn_w, wbh, wbl);
    k_conv<<<dim3(64, 4, 4), 256, 0, stream>>>(xbh, xbl, wbh, wbl, hpart);
    k_convreduce<<<4096, 256, 0, stream>>>(hpart, rpn_b, h);
    k_heads<<<128, 256, 0, stream>>>(h, cls_w, cls_b, tfm_w, tfm_b, anch,
                                     out_rpncls, out_rpntfm, ukey, bxp, byp, bwp, bhp, hist);
    k_scan<<<1, 1024, 0, stream>>>(hist, meta);
    k_compact<<<144, 256, 0, stream>>>(ukey, meta, cand, meta + 1);
    k_sort<<<1, 1024, 0, stream>>>(cand, meta, bxp, byp, bwp, bhp, rbx, rby, rbw, rbh);
    k_mask<<<2000, 256, 0, stream>>>(rbx, rby, rbw, rbh, mask);
    k_nms<<<1, 64, 0, stream>>>(mask, rbx, rby, rbw, rbh, sel, rxs, rys, rws_p, rhs_p,
                                cand);
    k_align<<<dim3(256, 4, 2), 256, 0, stream>>>(fmt, rxs, rys, rws_p, rhs_p, featsb);
    k_gemm<<<dim3(98, 4), 256, 0, stream>>>(featsb, hwb, part);
    k_reduce<<<105, 256, 0, stream>>>(part, head_b, out_fcls, out_ftfm);
    k_final<<<1, 256, 0, stream>>>(out_fcls, out_ftfm, rxs, rys, rws_p, rhs_p,
                                   out_prop, out_fbox);
}

// Round 12
// 343.759 us; speedup vs baseline: 1.3418x; 1.1496x over previous
//
#include <hip/hip_runtime.h>
#include <math.h>

// ---------------- problem constants ----------------
#define NPX   4096
#define NSC   36864
#define NKPRE 2000
#define NKPOST 256
#define GKS   98        // head-gemm K splits (K chunk 512)
#define CSPL  4         // conv K-splits (18 of 72 ksteps each)

// ---------------- ws layout (float offsets) ----------------
#define F_HPART  0
#define F_PART   0
#define F_H      4194304
#define F_FMT    5242880
#define F_XBH    6291456
#define F_XBL    6849024
#define F_WBH    7406592
#define F_WBL    7701504
#define F_FEATSB 6291456
#define F_HWB    12713984
#define F_UKEY   15523840
#define F_BX     15560704
#define F_BY     15597568
#define F_BW     15634432
#define F_BH     15671296
#define F_HIST   15708160
#define F_CAND   15773696
#define F_MASK   15781888
#define F_RBX    15909888
#define F_RBY    15911888
#define F_RBW    15913888
#define F_RBH    15915888
#define F_SEL    15917888
#define F_RXS    15918144
#define F_RYS    15918400
#define F_RWS    15918656
#define F_RHS    15918912
#define F_META   15919168
#define F_PRANK  15919184
// total = 15,923,280 floats = 63,693,120 bytes (< proven 64,037,184)

typedef unsigned long long u64;
typedef unsigned int u32;
typedef unsigned short ushort;
typedef __attribute__((ext_vector_type(8))) short short8;   // 8 bf16
typedef __attribute__((ext_vector_type(4))) float floatx4;  // MFMA acc

__device__ __forceinline__ ushort f2bf(float f) {
    u32 b = __float_as_uint(f);
    b += 0x7FFFu + ((b >> 16) & 1u);
    return (ushort)(b >> 16);
}
__device__ __forceinline__ float bf2f(ushort h) {
    return __uint_as_float(((u32)h) << 16);
}
__device__ __forceinline__ u64 RL64(u64 v, int l) {
    u32 lo = (u32)__builtin_amdgcn_readlane((int)(u32)v, l);
    u32 hi = (u32)__builtin_amdgcn_readlane((int)(u32)(v >> 32), l);
    return ((u64)hi << 32) | lo;
}

// ---------------- init: zero hist + meta + prank ----------------
__global__ void k_init(int* __restrict__ hist, int* __restrict__ meta,
                       int* __restrict__ prank) {
    int i = blockIdx.x * 256 + threadIdx.x;
    if (i < 65536) hist[i] = 0;
    if (i < 16) meta[i] = 0;
    if (i < 4096) prank[i] = 0;
}

// ---------------- head_w fp32 -> hwb bf16 [112][50176] ----------------
__global__ void k_hwb(const float* __restrict__ head_w, ushort* __restrict__ hwb) {
    int e = (blockIdx.x * 256 + threadIdx.x) * 4;
    int o = e / 50176, k = e % 50176;
    ushort4 r;
    if (o < 105) {
        float4 v = *(const float4*)(head_w + (size_t)o * 50176 + k);
        r.x = f2bf(v.x); r.y = f2bf(v.y); r.z = f2bf(v.z); r.w = f2bf(v.w);
    } else {
        r.x = r.y = r.z = r.w = 0;
    }
    *(ushort4*)(hwb + (size_t)o * 50176 + k) = r;
}

// ---------------- transpose x (C,H,W) -> fmt (H*W, C) ----------------
__global__ void __launch_bounds__(256) k_transpose(const float* __restrict__ x,
                                                   float* __restrict__ fmt) {
    __shared__ float t[64][65];
    int pt = blockIdx.x;
    int ct = blockIdx.y;
    int tid = threadIdx.x;
    int px0 = pt * 64, c0 = ct * 64;
    int ln = tid & 63, sub = tid >> 6;
    for (int p = 0; p < 16; ++p) {
        int cl = p * 4 + sub;
        t[ln][cl] = x[(c0 + cl) * 4096 + px0 + ln];
    }
    __syncthreads();
    for (int p = 0; p < 16; ++p) {
        int pl = p * 4 + sub;
        fmt[(px0 + pl) * 256 + c0 + ln] = t[pl][ln];
    }
}

// ---------------- build padded px-major split-bf16 image from fmt ----------------
__global__ void k_xb(const float* __restrict__ fmt, ushort* __restrict__ xbh,
                     ushort* __restrict__ xbl) {
    int e = blockIdx.x * 256 + threadIdx.x;     // < 278784
    int p = e >> 6, cq = (e & 63) * 4;
    int yy = p / 66, xx = p % 66;
    float4 v = {0.f, 0.f, 0.f, 0.f};
    if (yy >= 1 && yy <= 64 && xx >= 1 && xx <= 64)
        v = *(const float4*)&fmt[((yy - 1) * 64 + (xx - 1)) * 256 + cq];
    ushort4 h, l;
    h.x = f2bf(v.x); l.x = f2bf(v.x - bf2f(h.x));
    h.y = f2bf(v.y); l.y = f2bf(v.y - bf2f(h.y));
    h.z = f2bf(v.z); l.z = f2bf(v.z - bf2f(h.z));
    h.w = f2bf(v.w); l.w = f2bf(v.w - bf2f(h.w));
    *(ushort4*)&xbh[(size_t)p * 256 + cq] = h;
    *(ushort4*)&xbl[(size_t)p * 256 + cq] = l;
}

// ---------------- build per-tap split-bf16 weights wb{h,l}[t][oc][c] ----------------
__global__ void k_wb(const float* __restrict__ rpn_w, ushort* __restrict__ wbh,
                     ushort* __restrict__ wbl) {
    int e = blockIdx.x * 256 + threadIdx.x;     // e = t*65536 + oc*256 + c
    int c = e & 255, oc = (e >> 8) & 255, t = e >> 16;
    float v = rpn_w[oc * 2304 + c * 9 + t];
    ushort h = f2bf(v);
    wbh[e] = h;
    wbl[e] = f2bf(v - bf2f(h));
}

// ---------------- conv3x3 v6: split-bf16 MFMA implicit GEMM ----------------
__global__ void __launch_bounds__(256) k_conv(const ushort* __restrict__ xbh,
        const ushort* __restrict__ xbl, const ushort* __restrict__ wbh,
        const ushort* __restrict__ wbl, float* __restrict__ hpart) {
    __shared__ ushort lah[64 * 40], lal[64 * 40];
    __shared__ ushort lbh[64 * 40], lbl[64 * 40];
    int y0 = blockIdx.x;
    int oc0 = blockIdx.y * 64;
    int ksp = blockIdx.z;
    int tid = threadIdx.x;
    int wave = tid >> 6, lane = tid & 63;
    int m16 = lane & 15, quad = lane >> 4;
    floatx4 acc[4];
    #pragma unroll
    for (int nt = 0; nt < 4; ++nt) acc[nt] = (floatx4){0.f, 0.f, 0.f, 0.f};
    int sr = tid >> 2, sch = (tid & 3) * 8;
    for (int ki = ksp * 18; ki < ksp * 18 + 18; ++ki) {
        int t = ki >> 3, cb = ki & 7;
        int dy = t / 3, dx = t % 3;
        __syncthreads();
        {
            int rA0 = (y0 + dy) * 66 + dx;
            size_t g = (size_t)(rA0 + sr) * 256 + cb * 32 + sch;
            *(short8*)&lah[sr * 40 + sch] = *(const short8*)&xbh[g];
            *(short8*)&lal[sr * 40 + sch] = *(const short8*)&xbl[g];
        }
        {
            size_t g = (size_t)t * 65536 + (size_t)(oc0 + sr) * 256 + cb * 32 + sch;
            *(short8*)&lbh[sr * 40 + sch] = *(const short8*)&wbh[g];
            *(short8*)&lbl[sr * 40 + sch] = *(const short8*)&wbl[g];
        }
        __syncthreads();
        short8 ah = *(const short8*)&lah[(wave * 16 + m16) * 40 + quad * 8];
        short8 al = *(const short8*)&lal[(wave * 16 + m16) * 40 + quad * 8];
        #pragma unroll
        for (int nt = 0; nt < 4; ++nt) {
            short8 bh = *(const short8*)&lbh[(nt * 16 + m16) * 40 + quad * 8];
            short8 bl = *(const short8*)&lbl[(nt * 16 + m16) * 40 + quad * 8];
            acc[nt] = __builtin_amdgcn_mfma_f32_16x16x32_bf16(al, bh, acc[nt], 0, 0, 0);
            acc[nt] = __builtin_amdgcn_mfma_f32_16x16x32_bf16(ah, bl, acc[nt], 0, 0, 0);
            acc[nt] = __builtin_amdgcn_mfma_f32_16x16x32_bf16(ah, bh, acc[nt], 0, 0, 0);
        }
    }
    float* hp = hpart + (size_t)ksp * 1048576;
    #pragma unroll
    for (int nt = 0; nt < 4; ++nt) {
        int oc = oc0 + nt * 16 + m16;
        #pragma unroll
        for (int reg = 0; reg < 4; ++reg) {
            int px = y0 * 64 + wave * 16 + quad * 4 + reg;
            hp[oc * 4096 + px] = acc[nt][reg];
        }
    }
}

// ---------------- K-split reduce + bias -> h ----------------
__global__ void k_convreduce(const float* __restrict__ hpart,
                             const float* __restrict__ rpn_b,
                             float* __restrict__ h) {
    int e = blockIdx.x * 256 + threadIdx.x;
    float s = 0.f;
    #pragma unroll
    for (int k = 0; k < CSPL; ++k) s += hpart[(size_t)k * 1048576 + e];
    h[e] = s + rpn_b[e >> 12];
}

// ---------------- rpn heads + decode + histogram ----------------
__global__ void __launch_bounds__(256) k_heads(const float* __restrict__ h,
        const float* __restrict__ cls_w, const float* __restrict__ cls_b,
        const float* __restrict__ tfm_w, const float* __restrict__ tfm_b,
        const float* __restrict__ anchors,
        float* __restrict__ out_cls, float* __restrict__ out_tfm,
        u32* __restrict__ ukey, float* __restrict__ bxp, float* __restrict__ byp,
        float* __restrict__ bwp, float* __restrict__ bhp, int* __restrict__ hist) {
    __shared__ float w[256 * 56];
    __shared__ float ds[32 * 55];
    int tid = threadIdx.x;
    int px0 = blockIdx.x * 32;
    for (int e = tid; e < 54 * 256; e += 256) {
        int o = e >> 8, c = e & 255;
        float v = (o < 18) ? cls_w[o * 256 + c] : tfm_w[(o - 18) * 256 + c];
        w[c * 56 + o] = v;
    }
    __syncthreads();
    int ploc = tid & 31, og = tid >> 5;
    int px = px0 + ploc;
    float acc[7];
    #pragma unroll
    for (int j = 0; j < 7; ++j) acc[j] = 0.f;
    for (int c = 0; c < 256; ++c) {
        float hv = h[c * 4096 + px];
        #pragma unroll
        for (int j = 0; j < 7; ++j) acc[j] += hv * w[c * 56 + og * 7 + j];
    }
    #pragma unroll
    for (int j = 0; j < 7; ++j) {
        int o = og * 7 + j;
        if (o < 54) {
            float b = (o < 18) ? cls_b[o] : tfm_b[o - 18];
            float val = acc[j] + b;
            if (o < 18) out_cls[o * 4096 + px] = val;
            else        out_tfm[(o - 18) * 4096 + px] = val;
            ds[ploc * 55 + o] = val;
        }
    }
    __syncthreads();
    for (int t = tid; t < 288; t += 256) {
        int a = t >> 5, p = t & 31;
        int pxx = px0 + p;
        float pos = ds[p * 55 + 2 * a];
        float neg = ds[p * 55 + 2 * a + 1];
        float d = pos - neg;
        float sc = 1.f / (1.f + expf(-d));
        float t0 = ds[p * 55 + 18 + 4 * a + 0];
        float t1 = ds[p * 55 + 18 + 4 * a + 1];
        float t2 = ds[p * 55 + 18 + 4 * a + 2];
        float t3 = ds[p * 55 + 18 + 4 * a + 3];
        float ah = anchors[a * 2 + 0], aw = anchors[a * 2 + 1];
        float jx = (float)(pxx & 63), iy = (float)(pxx >> 6);
        float bx = jx + aw * (t1 - 0.5f) / 16.f;
        float by = iy + ah * (t0 - 0.5f) / 16.f;
        float bw = aw / 16.f * expf(t3);
        float bh = ah / 16.f * expf(t2);
        bx = fminf(fmaxf(bx, 0.f), 63.f);
        by = fminf(fmaxf(by, 0.f), 63.f);
        bw = fminf(fmaxf(bx + bw, 0.f), 63.f) - bx;
        bh = fminf(fmaxf(by + bh, 0.f), 63.f) - by;
        int idx = a * 4096 + pxx;
        u32 bits = __float_as_uint(sc);
        u32 u = (bits & 0x80000000u) ? ~bits : (bits ^ 0x80000000u);
        ukey[idx] = u;
        bxp[idx] = bx; byp[idx] = by; bwp[idx] = bw; bhp[idx] = bh;
        atomicAdd(&hist[u >> 16], 1);
    }
}

// ---------------- find cutoff bin for top-2000 ----------------
__global__ void __launch_bounds__(1024) k_scan(const int* __restrict__ hist,
                                               int* __restrict__ meta) {
    __shared__ int s[1024];
    int t = threadIdx.x;
    int base = 65536 - 64 * (t + 1);
    int sum = 0;
    for (int i = 0; i < 64; ++i) sum += hist[base + i];
    s[t] = sum;
    __syncthreads();
    int own = sum;
    for (int off = 1; off < 1024; off <<= 1) {
        int v = (t >= off) ? s[t - off] : 0;
        __syncthreads();
        s[t] += v;
        __syncthreads();
    }
    int cum = s[t], prev = cum - own;
    if (prev < NKPRE && cum >= NKPRE) {
        int c = prev;
        int b = 65535 - 64 * t;
        for (int i = 0; i < 64; ++i) {
            c += hist[b - i];
            if (c >= NKPRE) { meta[0] = b - i; break; }
        }
    }
}

// ---------------- compact candidates (bin >= cutoff) ----------------
__global__ void k_compact(const u32* __restrict__ ukey, const int* __restrict__ meta,
                          u64* __restrict__ cand, int* __restrict__ cnt) {
    int i = blockIdx.x * 256 + threadIdx.x;
    if (i >= NSC) return;
    u32 u = ukey[i];
    if ((int)(u >> 16) >= meta[0]) {
        int pos = atomicAdd(cnt, 1);
        if (pos < 4096) cand[pos] = (((u64)(~u)) << 32) | (u32)i;
    }
}

// ---------------- rank candidates: prank[i] = #{j : key_j < key_i} ----------------
// grid (16 i-slices, 16 j-chunks) x 256 threads; chunk of 256 keys in LDS.
__global__ void __launch_bounds__(256) k_rank(const u64* __restrict__ cand,
                                              int* __restrict__ prank) {
    __shared__ u64 sk[256];
    int tid = threadIdx.x;
    int i = blockIdx.x * 256 + tid;
    int j0 = blockIdx.y * 256;
    sk[tid] = cand[j0 + tid];
    __syncthreads();
    u64 mykey = cand[i];
    int r = 0;
    #pragma unroll 8
    for (int j = 0; j < 256; j += 2) {
        ulonglong2 kv = *(const ulonglong2*)&sk[j];
        r += (kv.x < mykey) ? 1 : 0;
        r += (kv.y < mykey) ? 1 : 0;
    }
    atomicAdd(&prank[i], r);
}

// ---------------- place top-2000 boxes by rank ----------------
__global__ void k_place(const u64* __restrict__ cand, const int* __restrict__ meta,
        const int* __restrict__ prank,
        const float* __restrict__ bxp, const float* __restrict__ byp,
        const float* __restrict__ bwp, const float* __restrict__ bhp,
        float* __restrict__ rbx, float* __restrict__ rby,
        float* __restrict__ rbw, float* __restrict__ rbh) {
    int i = blockIdx.x * 256 + threadIdx.x;
    int vc = meta[1]; if (vc > 4096) vc = 4096;
    if (i >= vc) return;
    int r = prank[i];
    if (r >= NKPRE) return;
    int idx = (int)(u32)(cand[i] & 0xFFFFFFFFULL);
    rbx[r] = bxp[idx]; rby[r] = byp[idx]; rbw[r] = bwp[idx]; rbh[r] = bhp[idx];
}

// ---------------- IoU suppression bitmask ----------------
__global__ void __launch_bounds__(256) k_mask(const float* __restrict__ rbx,
        const float* __restrict__ rby, const float* __restrict__ rbw,
        const float* __restrict__ rbh, u64* __restrict__ mask) {
    int i = blockIdx.x;
    int lane = threadIdx.x & 63;
    int wave = threadIdx.x >> 6;
    float bxi = rbx[i], byi = rby[i], bwi = rbw[i], bhi = rbh[i];
    float x2i = bxi + bwi, y2i = byi + bhi, ari = bwi * bhi;
    for (int w = wave; w < 32; w += 4) {
        int j = w * 64 + lane;
        bool p = false;
        if (j < NKPRE && j > i) {
            float bxj = rbx[j], byj = rby[j], bwj = rbw[j], bhj = rbh[j];
            float x2j = bxj + bwj, y2j = byj + bhj, arj = bwj * bhj;
            float ix = fmaxf(bxi, bxj), iy = fmaxf(byi, byj);
            float iw = fmaxf(fminf(x2i, x2j) - ix, 0.f);
            float ih = fmaxf(fminf(y2i, y2j) - iy, 0.f);
            float inter = iw * ih;
            float iou = inter / (ari + arj - inter);
            p = iou > 0.7f;
        }
        u64 b = __ballot(p);
        if (lane == 0) mask[i * 32 + w] = b;
    }
}

// ---------------- greedy NMS v2 ----------------
__global__ void __launch_bounds__(64) k_nms(const u64* __restrict__ mask,
        const float* __restrict__ rbx, const float* __restrict__ rby,
        const float* __restrict__ rbw, const float* __restrict__ rbh,
        int* __restrict__ sel, float* __restrict__ rxs, float* __restrict__ rys,
        float* __restrict__ rws, float* __restrict__ rhs,
        u64* __restrict__ scratch) {
    __shared__ int klist[256];
    int lane = threadIdx.x;
    int lw = lane & 31;
    {
        const ulonglong2* m2 = (const ulonglong2*)mask;
        u64 acc = 0;
        #pragma unroll 25
        for (int it = lane; it < 32000; it += 64) {
            ulonglong2 v = m2[it];
            acc |= v.x | v.y;
        }
        scratch[lane] = acc;
    }
    u64 removed = 0ULL;
    int kcount = 0;
    u64 pf[32];
    #pragma unroll
    for (int s = 0; s < 32; ++s) pf[s] = mask[s * 32 + lw];
    bool done = false;
    for (int ib = 0; ib < NKPRE; ib += 32) {
        if (done) break;
        int cw = ib >> 6;
        int iw = (ib + 32) >> 6;
        u64 remC = RL64(removed, cw);
        u64 remI = RL64(removed, iw);
        #pragma unroll
        for (int s = 0; s < 32; ++s) {
            int ii = ib + s;
            u64 row = pf[s];
            int nx = ii + 32;
            if (!done && nx < NKPRE && !((remI >> (nx & 63)) & 1ULL))
                pf[s] = mask[(size_t)nx * 32 + lw];
            if (!done && ii < NKPRE && !((remC >> (ii & 63)) & 1ULL)) {
                if (lane == 0) klist[kcount] = ii;
                kcount++;
                if (lane < 32) removed |= row;
                remC |= RL64(row, cw);
                remI |= RL64(row, iw);
                if (kcount == NKPOST) done = true;
            }
        }
    }
    if (kcount < NKPOST) {
        for (int w = 0; w < 32 && kcount < NKPOST; ++w) {
            u64 wv = RL64(removed, w);
            int base = w << 6;
            for (int b = 0; b < 64; ++b) {
                int ii = base + b;
                if (ii >= NKPRE || kcount >= NKPOST) break;
                if ((wv >> b) & 1ULL) {
                    if (lane == 0) klist[kcount] = ii;
                    kcount++;
                }
            }
        }
    }
    __syncthreads();
    for (int s = lane; s < NKPOST; s += 64) {
        int id = klist[s];
        sel[s] = id;
        rxs[s] = rbx[id]; rys[s] = rby[id]; rws[s] = rbw[id]; rhs[s] = rbh[id];
    }
}

// ---------------- ROI align v3: bf16 output feats ----------------
__global__ void __launch_bounds__(256) k_align(const float* __restrict__ fmt,
        const float* __restrict__ rxs, const float* __restrict__ rys,
        const float* __restrict__ rws, const float* __restrict__ rhs,
        ushort* __restrict__ feats) {
    __shared__ float buf[64 * 99];
    __shared__ int xs0[28], ys0[28];
    __shared__ float wxs[28], wys[28];
    int roi = blockIdx.x;
    int c0 = blockIdx.y * 64;
    int ch0 = blockIdx.z * 98;
    int tid = threadIdx.x;
    float rx = rxs[roi], ry = rys[roi], rw = rws[roi], rh = rhs[roi];
    if (tid < 28) {
        float g = rx + ((float)tid + 0.5f) * rw / 28.f;
        g = fminf(fmaxf(g, 0.f), 63.f);
        int x0 = (int)floorf(g); x0 = min(max(x0, 0), 62);
        xs0[tid] = x0; wxs[tid] = g - (float)x0;
        float g2 = ry + ((float)tid + 0.5f) * rh / 28.f;
        g2 = fminf(fmaxf(g2, 0.f), 63.f);
        int y0 = (int)floorf(g2); y0 = min(max(y0, 0), 62);
        ys0[tid] = y0; wys[tid] = g2 - (float)y0;
    }
    __syncthreads();
    int cl = tid & 63, cg = tid >> 6;
    for (int l = cg; l < 98; l += 4) {
        int cell = ch0 + l;
        int py = cell / 14, pxc = cell % 14;
        float m = -INFINITY;
        #pragma unroll
        for (int dy = 0; dy < 2; ++dy) {
            int sy = py * 2 + dy;
            int y0 = ys0[sy]; float wy = wys[sy];
            #pragma unroll
            for (int dx = 0; dx < 2; ++dx) {
                int sx = pxc * 2 + dx;
                int x0 = xs0[sx]; float wx = wxs[sx];
                int base = (y0 * 64 + x0) * 256 + c0 + cl;
                float f00 = fmt[base];
                float f10 = fmt[base + 256];
                float f01 = fmt[base + 64 * 256];
                float f11 = fmt[base + 64 * 256 + 256];
                float v = f00 * (1.f - wy) * (1.f - wx) + f01 * wy * (1.f - wx)
                        + f10 * (1.f - wy) * wx + f11 * wy * wx;
                m = fmaxf(m, v);
            }
        }
        buf[cl * 99 + l] = m;
    }
    __syncthreads();
    for (int e = tid; e < 64 * 98; e += 256) {
        int c = e / 98, l = e % 98;
        feats[(size_t)roi * 50176 + (c0 + c) * 196 + ch0 + l] = f2bf(buf[c * 99 + l]);
    }
}

// ---------------- head GEMM v6: bf16 MFMA, no LDS, no barriers ----------------
__global__ void __launch_bounds__(256) k_gemm(const ushort* __restrict__ fb,
        const ushort* __restrict__ hwb, float* __restrict__ part) {
    int ks = blockIdx.x, rt = blockIdx.y;
    int wave = threadIdx.x >> 6, lane = threadIdx.x & 63;
    int m16 = lane & 15, quad = lane >> 4;
    int roiBase = rt * 64 + wave * 16;
    int kb = ks * 512;
    const ushort* arow = fb + (size_t)(roiBase + m16) * 50176 + kb + quad * 8;
    const ushort* brow = hwb + (size_t)m16 * 50176 + kb + quad * 8;
    floatx4 acc[7];
    #pragma unroll
    for (int t = 0; t < 7; ++t) acc[t] = (floatx4){0.f, 0.f, 0.f, 0.f};
    #pragma unroll 4
    for (int step = 0; step < 16; ++step) {
        short8 a = *(const short8*)(arow + step * 32);
        #pragma unroll
        for (int t = 0; t < 7; ++t) {
            short8 b = *(const short8*)(brow + (size_t)t * 16 * 50176 + step * 32);
            acc[t] = __builtin_amdgcn_mfma_f32_16x16x32_bf16(a, b, acc[t], 0, 0, 0);
        }
    }
    float* pbase = part + (size_t)ks * 26880;
    #pragma unroll
    for (int t = 0; t < 7; ++t) {
        int o = t * 16 + m16;
        if (o < 105) {
            #pragma unroll
            for (int reg = 0; reg < 4; ++reg) {
                int roi = roiBase + quad * 4 + reg;
                pbase[roi * 105 + o] = acc[t][reg];
            }
        }
    }
}

// ---------------- deterministic K-split reduce + bias ----------------
__global__ void k_reduce(const float* __restrict__ part, const float* __restrict__ head_b,
                         float* __restrict__ out_cls, float* __restrict__ out_tfm) {
    int e = blockIdx.x * 256 + threadIdx.x;
    if (e >= 26880) return;
    int roi = e / 105, o = e % 105;
    float s = 0.f;
    for (int ks = 0; ks < GKS; ++ks) s += part[(size_t)ks * 26880 + e];
    s += head_b[o];
    if (o < 21) out_cls[roi * 21 + o] = s;
    else        out_tfm[roi * 84 + (o - 21)] = s;
}

// ---------------- argmax + final/proposal bbox ----------------
__global__ void __launch_bounds__(256) k_final(const float* __restrict__ out_cls,
        const float* __restrict__ out_tfm,
        const float* __restrict__ rxs, const float* __restrict__ rys,
        const float* __restrict__ rws, const float* __restrict__ rhs,
        float* __restrict__ prop, float* __restrict__ fbox) {
    int r = threadIdx.x;
    float best = out_cls[r * 21]; int det = 0;
    for (int o = 1; o < 21; ++o) {
        float v = out_cls[r * 21 + o];
        if (v > best) { best = v; det = o; }
    }
    float t0 = out_tfm[r * 84 + det * 4 + 0];
    float t1 = out_tfm[r * 84 + det * 4 + 1];
    float t2 = out_tfm[r * 84 + det * 4 + 2];
    float t3 = out_tfm[r * 84 + det * 4 + 3];
    float X = rxs[r] * 16.f, Y = rys[r] * 16.f, Wd = rws[r] * 16.f, Hd = rhs[r] * 16.f;
    float fx = X + Wd * t1, fy = Y + Hd * t0;
    float fw = Wd * expf(t3), fh = Hd * expf(t2);
    prop[r * 5 + 0] = 0.f; prop[r * 5 + 1] = X;  prop[r * 5 + 2] = Y;
    prop[r * 5 + 3] = Wd;  prop[r * 5 + 4] = Hd;
    fbox[r * 5 + 0] = 0.f; fbox[r * 5 + 1] = fx; fbox[r * 5 + 2] = fy;
    fbox[r * 5 + 3] = fw;  fbox[r * 5 + 4] = fh;
}

extern "C" void kernel_launch(void* const* d_in, const int* in_sizes, int n_in,
                              void* d_out, int out_size, void* d_ws, size_t ws_size,
                              hipStream_t stream) {
    const float* x      = (const float*)d_in[0];
    const float* rpn_w  = (const float*)d_in[1];
    const float* rpn_b  = (const float*)d_in[2];
    const float* cls_w  = (const float*)d_in[3];
    const float* cls_b  = (const float*)d_in[4];
    const float* tfm_w  = (const float*)d_in[5];
    const float* tfm_b  = (const float*)d_in[6];
    const float* head_w = (const float*)d_in[7];
    const float* head_b = (const float*)d_in[8];
    const float* anch   = (const float*)d_in[9];
    float* out = (float*)d_out;
    float* ws  = (float*)d_ws;

    float*  hpart  = ws + F_HPART;
    float*  h      = ws + F_H;
    float*  fmt    = ws + F_FMT;
    ushort* xbh    = (ushort*)(ws + F_XBH);
    ushort* xbl    = (ushort*)(ws + F_XBL);
    ushort* wbh    = (ushort*)(ws + F_WBH);
    ushort* wbl    = (ushort*)(ws + F_WBL);
    ushort* featsb = (ushort*)(ws + F_FEATSB);
    ushort* hwb    = (ushort*)(ws + F_HWB);
    float*  part   = ws + F_PART;
    u32*    ukey   = (u32*)(ws + F_UKEY);
    float*  bxp    = ws + F_BX;
    float*  byp    = ws + F_BY;
    float*  bwp    = ws + F_BW;
    float*  bhp    = ws + F_BH;
    int*    hist   = (int*)(ws + F_HIST);
    u64*    cand   = (u64*)(ws + F_CAND);
    u64*    mask   = (u64*)(ws + F_MASK);
    float*  rbx    = ws + F_RBX;
    float*  rby    = ws + F_RBY;
    float*  rbw    = ws + F_RBW;
    float*  rbh    = ws + F_RBH;
    int*    sel    = (int*)(ws + F_SEL);
    float*  rxs    = ws + F_RXS;
    float*  rys    = ws + F_RYS;
    float*  rws_p  = ws + F_RWS;
    float*  rhs_p  = ws + F_RHS;
    int*    meta   = (int*)(ws + F_META);
    int*    prank  = (int*)(ws + F_PRANK);

    float* out_rpncls = out + 0;
    float* out_rpntfm = out + 73728;
    float* out_prop   = out + 221184;
    float* out_fbox   = out + 222464;
    float* out_fcls   = out + 223744;
    float* out_ftfm   = out + 229120;

    k_init<<<256, 256, 0, stream>>>(hist, meta, prank);
    k_hwb<<<5488, 256, 0, stream>>>(head_w, hwb);
    k_transpose<<<dim3(64, 4), 256, 0, stream>>>(x, fmt);
    k_xb<<<1089, 256, 0, stream>>>(fmt, xbh, xbl);
    k_wb<<<2304, 256, 0, stream>>>(rpn_w, wbh, wbl);
    k_conv<<<dim3(64, 4, 4), 256, 0, stream>>>(xbh, xbl, wbh, wbl, hpart);
    k_convreduce<<<4096, 256, 0, stream>>>(hpart, rpn_b, h);
    k_heads<<<128, 256, 0, stream>>>(h, cls_w, cls_b, tfm_w, tfm_b, anch,
                                     out_rpncls, out_rpntfm, ukey, bxp, byp, bwp, bhp, hist);
    k_scan<<<1, 1024, 0, stream>>>(hist, meta);
    k_compact<<<144, 256, 0, stream>>>(ukey, meta, cand, meta + 1);
    k_rank<<<dim3(16, 16), 256, 0, stream>>>(cand, prank);
    k_place<<<16, 256, 0, stream>>>(cand, meta, prank, bxp, byp, bwp, bhp,
                                    rbx, rby, rbw, rbh);
    k_mask<<<2000, 256, 0, stream>>>(rbx, rby, rbw, rbh, mask);
    k_nms<<<1, 64, 0, stream>>>(mask, rbx, rby, rbw, rbh, sel, rxs, rys, rws_p, rhs_p,
                                cand);
    k_align<<<dim3(256, 4, 2), 256, 0, stream>>>(fmt, rxs, rys, rws_p, rhs_p, featsb);
    k_gemm<<<dim3(98, 4), 256, 0, stream>>>(featsb, hwb, part);
    k_reduce<<<105, 256, 0, stream>>>(part, head_b, out_fcls, out_ftfm);
    k_final<<<1, 256, 0, stream>>>(out_fcls, out_ftfm, rxs, rys, rws_p, rhs_p,
                                   out_prop, out_fbox);
}